// Round 9
// baseline (886.102 us; speedup 1.0000x reference)
//
#include <hip/hip_runtime.h>
#include <hip/hip_bf16.h>
#include <stdint.h>

typedef __bf16 bf16;
typedef __bf16 bf16x4 __attribute__((ext_vector_type(4)));
typedef __bf16 bf16x8 __attribute__((ext_vector_type(8)));
typedef float  f32x4  __attribute__((ext_vector_type(4)));
typedef unsigned int u32;

__device__ __forceinline__ f32x4 mfma16(bf16x8 a, bf16x8 b, f32x4 c) {
    return __builtin_amdgcn_mfma_f32_16x16x32_bf16(a, b, c, 0, 0, 0);
}
__device__ __forceinline__ void st_bf4(bf16* p, float a, float b, float c, float d) {
    bf16x4 v = { (bf16)a, (bf16)b, (bf16)c, (bf16)d };
    *(bf16x4*)p = v;
}
// async global->LDS, 16B per lane; LDS dest = wave-uniform base + lane*16
__device__ __forceinline__ void gl16(const bf16* g, bf16* l) {
    __builtin_amdgcn_global_load_lds(
        (const __attribute__((address_space(1))) u32*)g,
        (__attribute__((address_space(3))) u32*)l, 16, 0, 0);
}

// ---------------------------------------------------------------------------
// weights f32 -> bf16.  qkvw/projw linear; fc12w/fc2w permuted into
// per-wave-fragment order so one wave load = 1 KB contiguous.
// ---------------------------------------------------------------------------
__global__ __launch_bounds__(256) void k_cvtw(
    const float* __restrict__ qkvw, const float* __restrict__ projw,
    const float* __restrict__ f12w, const float* __restrict__ f2w,
    bf16* __restrict__ wb)
{
    const int i = blockIdx.x * 256 + threadIdx.x;   // one 8-elem chunk
    const size_t doff = (size_t)i * 8;
    const float* src; size_t soff;
    if (i < 24576) {            // qkv linear (196608 elems)
        src = qkvw; soff = doff;
    } else if (i < 32768) {     // proj linear (65536)
        src = projw; soff = doff - 196608;
    } else if (i < 98304) {     // w12f permuted (524288)
        const int i3 = i - 32768;
        const int hrow16 = i3 >> 9, ks = (i3 >> 6) & 7, l = i3 & 63;
        src = f12w;
        soff = (size_t)(hrow16*16 + (l&15))*256 + ks*32 + (l>>4)*8;
    } else {                    // w2f permuted (262144)
        const int i4 = i - 98304;
        const int ob = i4 >> 11, kc = (i4 >> 6) & 31, l = i4 & 63;
        src = f2w;
        soff = (size_t)(ob*16 + (l&15))*1024 + kc*32 + (l>>4)*8;
    }
    float4 a = *(const float4*)(src + soff);
    float4 b = *(const float4*)(src + soff + 4);
    bf16x8 v = { (bf16)a.x,(bf16)a.y,(bf16)a.z,(bf16)a.w,
                 (bf16)b.x,(bf16)b.y,(bf16)b.z,(bf16)b.w };
    *(bf16x8*)(wb + doff) = v;
}

// ---------------------------------------------------------------------------
// bias+mask table: tab[type][h][m(key)][n(query)], 4*8*64*64 = 131072 f32
// ---------------------------------------------------------------------------
__global__ __launch_bounds__(256) void k_mkbias(
    const float* __restrict__ rpb, float* __restrict__ tab)
{
    const int idx = blockIdx.x * 256 + threadIdx.x;
    const int type = idx >> 15, h = (idx >> 12) & 7, m = (idx >> 6) & 63, n = idx & 63;
    const int mr = m >> 3, mc = m & 7, nr = n >> 3, nc = n & 7;
    float bv = rpb[((nr - mr + 7) * 15 + (nc - mc + 7)) * 8 + h];
    const int ter = type >> 1, tec = type & 1;
    const int hm = ter ? ((mr < 4) ? 1 : 2) : 0;
    const int wm = tec ? ((mc < 4) ? 1 : 2) : 0;
    const int hn = ter ? ((nr < 4) ? 1 : 2) : 0;
    const int wn = tec ? ((nc < 4) ? 1 : 2) : 0;
    if (hm != hn || wm != wn) bv -= 100.f;
    tab[idx] = bv;
}

// ---------------------------------------------------------------------------
// LN1 + window gather: output rows in window order (b,win,tok)
// ---------------------------------------------------------------------------
__global__ __launch_bounds__(256) void k_ln_win(
    const float* __restrict__ in, const float* __restrict__ gw_,
    const float* __restrict__ gb_, bf16* __restrict__ o)
{
    const int tid = threadIdx.x;
    const int wv = tid >> 6, ln = tid & 63;
    const size_t drow = (size_t)blockIdx.x * 4 + wv;
    const int b = drow >> 12, win = (drow >> 6) & 63, tok = drow & 63;
    const int wr = win >> 3, wc = win & 7, tr = tok >> 3, tc = tok & 7;
    const int hs = (wr * 8 + tr + 4) & 63, vs = (wc * 8 + tc + 4) & 63;
    const size_t srow = ((size_t)b << 12) | (hs << 6) | vs;
    const float* src = in + srow * 256;
    float4 v = *(const float4*)(src + ln * 4);
    float s = v.x + v.y + v.z + v.w;
    float q = v.x*v.x + v.y*v.y + v.z*v.z + v.w*v.w;
    #pragma unroll
    for (int ofs = 32; ofs; ofs >>= 1) { s += __shfl_xor(s, ofs); q += __shfl_xor(q, ofs); }
    const float mean = s * (1.0f/256.0f);
    const float var  = q * (1.0f/256.0f) - mean * mean;
    const float rstd = rsqrtf(var + 1e-5f);
    float4 gw = *(const float4*)(gw_ + ln*4);
    float4 gb = *(const float4*)(gb_ + ln*4);
    st_bf4(o + drow*256 + ln*4,
           (v.x-mean)*rstd*gw.x + gb.x, (v.y-mean)*rstd*gw.y + gb.y,
           (v.z-mean)*rstd*gw.z + gb.z, (v.w-mean)*rstd*gw.w + gb.w);
}

// ---------------------------------------------------------------------------
// QKV GEMM (window-ordered rows): Q/K linear window-major; V computed with
// SWAPPED mfma so the epilogue writes V^T [win][chan][tok] coalesced.
// Grid (6, 1024): N-blocks sharing an A-tile are dispatch-adjacent (L2 reuse).
// ---------------------------------------------------------------------------
__global__ __launch_bounds__(256) void k_qkv(
    const bf16* __restrict__ A, const bf16* __restrict__ Bw,
    const float* __restrict__ qkvb,
    bf16* __restrict__ Qb, bf16* __restrict__ Kb, bf16* __restrict__ Vt)
{
    __shared__ bf16 sA[128*32];
    __shared__ bf16 sB[128*32];
    const int tid = threadIdx.x, w = tid>>6, l = tid&63;
    const int l16 = l&15, lg = l>>4;
    const int wm = w>>1, wn = w&1;
    const int m0 = blockIdx.y<<7, n0 = blockIdx.x<<7;
    const bool vseg = (n0 >= 512);
    const int srow = l>>2;
    const int gk = ((l&3) ^ ((l>>3)&3)) << 3;
    const bf16* gA0 = A + (size_t)(m0 + w*32 + srow)*256 + gk;
    const bf16* gA1 = gA0 + 16*256;
    const bf16* gB0 = Bw + (size_t)(n0 + w*32 + srow)*256 + gk;
    const bf16* gB1 = gB0 + 16*256;
    bf16* lA0 = &sA[(w*32)*32];
    bf16* lA1 = &sA[(w*32+16)*32];
    bf16* lB0 = &sB[(w*32)*32];
    bf16* lB1 = &sB[(w*32+16)*32];
    const int slot = lg ^ ((l16>>1)&3);
    int adA[4], adB[4];
    #pragma unroll
    for (int i=0;i<4;++i) {
        adA[i] = (wm*64 + i*16 + l16)*32 + slot*8;
        adB[i] = (wn*64 + i*16 + l16)*32 + slot*8;
    }
    f32x4 acc[4][4] = {};
    for (int ks = 0; ks < 8; ++ks) {
        gl16(gA0 + ks*32, lA0); gl16(gA1 + ks*32, lA1);
        gl16(gB0 + ks*32, lB0); gl16(gB1 + ks*32, lB1);
        __syncthreads();
        bf16x8 av[4], bv[4];
        #pragma unroll
        for (int i=0;i<4;++i) { av[i] = *(const bf16x8*)&sA[adA[i]]; bv[i] = *(const bf16x8*)&sB[adB[i]]; }
        if (!vseg) {
            #pragma unroll
            for (int mi=0;mi<4;++mi)
                #pragma unroll
                for (int ni=0;ni<4;++ni)
                    acc[mi][ni] = mfma16(av[mi], bv[ni], acc[mi][ni]);
        } else {
            #pragma unroll
            for (int mi=0;mi<4;++mi)
                #pragma unroll
                for (int ni=0;ni<4;++ni)
                    acc[mi][ni] = mfma16(bv[ni], av[mi], acc[mi][ni]);
        }
        __syncthreads();
    }
    if (!vseg) {
        #pragma unroll
        for (int ni=0;ni<4;++ni) {
            const int cg = n0 + wn*64 + ni*16 + l16;
            const int seg = cg >> 8, cs = cg & 255;
            bf16* dst = (seg==0) ? Qb : Kb;
            const float mul = (seg==0) ? 0.1767766952966369f : 1.0f;
            const float bias = qkvb[cg];
            #pragma unroll
            for (int mi=0;mi<4;++mi) {
                const int row = m0 + wm*64 + mi*16 + lg*4;
                #pragma unroll
                for (int r=0;r<4;++r)
                    dst[(size_t)(row+r)*256 + cs] = (bf16)((acc[mi][ni][r] + bias)*mul);
            }
        }
    } else {
        const int winb = (m0 >> 6) + wm;
        #pragma unroll
        for (int ni=0;ni<4;++ni) {
            const int ch0 = (n0 - 512) + wn*64 + ni*16 + lg*4;
            const float4 b4 = *(const float4*)(qkvb + 512 + ch0);
            const float barr[4] = { b4.x, b4.y, b4.z, b4.w };
            #pragma unroll
            for (int mi=0;mi<4;++mi) {
                const int tok = mi*16 + l16;
                #pragma unroll
                for (int r=0;r<4;++r)
                    Vt[(size_t)winb*16384 + (size_t)(ch0+r)*64 + tok] =
                        (bf16)(acc[mi][ni][r] + barr[r]);
            }
        }
    }
}

// ---------------------------------------------------------------------------
// fused attention + proj + residual + LN2: one block per window.
// Head loop (barrier-free, global K/V^T via L2) -> sO in LDS -> proj GEMM
// (B-frags from L2, col-split per wave) -> LDS cross-wave LN2 reduction ->
// scatter epilogue (reverse shift) writing out (f32) and xn2 (bf16).
// LDS = sP 9 KB + sO 33 KB -> 3 blocks/CU.
// ---------------------------------------------------------------------------
__global__ __launch_bounds__(256) void k_attnproj(
    const bf16* __restrict__ Qb, const bf16* __restrict__ Kb,
    const bf16* __restrict__ Vt, const float* __restrict__ biasTab,
    const bf16* __restrict__ pw, const float* __restrict__ projb,
    const float* __restrict__ x, const float* __restrict__ n2w,
    const float* __restrict__ n2b, float* __restrict__ out,
    bf16* __restrict__ xn2)
{
    __shared__ bf16 sP[64][72];
    __shared__ bf16 sO[64][264];
    const int tid = threadIdx.x;
    const int wv = tid>>6, l = tid&63, l16 = l&15, lg = l>>4;
    const int win = blockIdx.x, ww = win&63;
    const int type = (((ww>>3)==7)?2:0) | (((ww&7)==7)?1:0);

    const bf16* Kw = Kb + (size_t)win*64*256;
    const bf16* Vw = Vt + (size_t)win*16384;

    const size_t qoff = ((size_t)win*64 + wv*16 + l16)*256 + lg*8;
    bf16x8 qf[8];
    #pragma unroll
    for (int h=0;h<8;++h) qf[h] = *(const bf16x8*)(Qb + qoff + h*32);

    bf16x8 kb[4];
    #pragma unroll
    for (int nt=0;nt<4;++nt)
        kb[nt] = *(const bf16x8*)(Kw + (size_t)(nt*16+l16)*256 + lg*8);

    const float* tb0 = biasTab + ((size_t)type<<15) + wv*16 + lg*4;

    for (int h=0; h<8; ++h) {
        const float* tb = tb0 + (h<<12);
        f32x4 at[4];
        #pragma unroll
        for (int nt=0;nt<4;++nt) {
            f32x4 bias4 = *(const f32x4*)(tb + (nt*16 + l16)*64);
            at[nt] = mfma16(qf[h], kb[nt], bias4);
        }
        if (h < 7) {
            #pragma unroll
            for (int nt=0;nt<4;++nt)
                kb[nt] = *(const bf16x8*)(Kw + (size_t)(nt*16+l16)*256 + (h+1)*32 + lg*8);
        }
        #pragma unroll
        for (int r=0;r<4;++r) {
            float mx = fmaxf(fmaxf(at[0][r],at[1][r]), fmaxf(at[2][r],at[3][r]));
            #pragma unroll
            for (int ofs=8;ofs;ofs>>=1) mx = fmaxf(mx, __shfl_xor(mx,ofs));
            float e0 = __expf(at[0][r]-mx), e1 = __expf(at[1][r]-mx);
            float e2 = __expf(at[2][r]-mx), e3 = __expf(at[3][r]-mx);
            float sm = e0+e1+e2+e3;
            #pragma unroll
            for (int ofs=8;ofs;ofs>>=1) sm += __shfl_xor(sm,ofs);
            const float inv = 1.0f/sm;
            const int n = wv*16 + lg*4 + r;
            sP[n][ 0+l16] = (bf16)(e0*inv);
            sP[n][16+l16] = (bf16)(e1*inv);
            sP[n][32+l16] = (bf16)(e2*inv);
            sP[n][48+l16] = (bf16)(e3*inv);
        }
        #pragma unroll
        for (int nt=0;nt<2;++nt) {
            f32x4 o = {};
            #pragma unroll
            for (int ks=0;ks<2;++ks) {
                bf16x8 pa = *(const bf16x8*)&sP[wv*16+l16][ks*32+lg*8];
                bf16x8 vb = *(const bf16x8*)(Vw + (size_t)(h*32+nt*16+l16)*64 + ks*32 + lg*8);
                o = mfma16(pa, vb, o);
            }
            #pragma unroll
            for (int r=0;r<4;++r)
                sO[wv*16 + lg*4 + r][h*32 + nt*16 + l16] = (bf16)o[r];
        }
    }
    __syncthreads();   // sO complete (and sP free for reuse as f32 sums)

    // ---- proj GEMM: wave wv covers out cols wv*64..+63, all 64 rows ----
    f32x4 acc[4][4] = {};
    for (int ks=0; ks<8; ++ks) {
        bf16x8 av[4];
        #pragma unroll
        for (int mi=0;mi<4;++mi)
            av[mi] = *(const bf16x8*)&sO[mi*16+l16][ks*32+lg*8];
        #pragma unroll
        for (int ni=0;ni<4;++ni) {
            bf16x8 bv = *(const bf16x8*)(pw + (size_t)(wv*64+ni*16+l16)*256 + ks*32 + lg*8);
            #pragma unroll
            for (int mi=0;mi<4;++mi)
                acc[mi][ni] = mfma16(av[mi], bv, acc[mi][ni]);
        }
    }
    // ---- residual add + per-wave partial row sums (LN2) ----
    float* sums = (float*)sP;   // [64 tok][8]: 0..3 = s per wave, 4..7 = s2
    const int b = win>>6;
    const int wr = ww>>3, wc = ww&7;
    #pragma unroll
    for (int mi=0;mi<4;++mi) {
        #pragma unroll
        for (int r=0;r<4;++r) {
            const int tok = mi*16 + lg*4 + r;
            const int tr = tok>>3, tc = tok&7;
            const int hs = (wr*8+tr+4)&63, vs = (wc*8+tc+4)&63;
            const size_t grow = ((size_t)b<<12) + (hs<<6) + vs;
            float s = 0.f, s2 = 0.f;
            #pragma unroll
            for (int ni=0;ni<4;++ni) {
                const int col = wv*64 + ni*16 + l16;
                float t = acc[mi][ni][r] + projb[col] + x[grow*256 + col];
                acc[mi][ni][r] = t;
                s += t; s2 += t*t;
            }
            #pragma unroll
            for (int ofs=8;ofs;ofs>>=1) { s += __shfl_xor(s,ofs); s2 += __shfl_xor(s2,ofs); }
            if (l16 == 0) { sums[tok*8 + wv] = s; sums[tok*8 + 4 + wv] = s2; }
        }
    }
    __syncthreads();
    // ---- LN2 + scatter writes ----
    #pragma unroll
    for (int mi=0;mi<4;++mi) {
        #pragma unroll
        for (int r=0;r<4;++r) {
            const int tok = mi*16 + lg*4 + r;
            const int tr = tok>>3, tc = tok&7;
            const int hs = (wr*8+tr+4)&63, vs = (wc*8+tc+4)&63;
            const size_t grow = ((size_t)b<<12) + (hs<<6) + vs;
            const float fs  = sums[tok*8+0]+sums[tok*8+1]+sums[tok*8+2]+sums[tok*8+3];
            const float fs2 = sums[tok*8+4]+sums[tok*8+5]+sums[tok*8+6]+sums[tok*8+7];
            const float mean = fs * (1.f/256.f);
            const float rstd = rsqrtf(fs2*(1.f/256.f) - mean*mean + 1e-5f);
            #pragma unroll
            for (int ni=0;ni<4;++ni) {
                const int col = wv*64 + ni*16 + l16;
                const float t = acc[mi][ni][r];
                out[grow*256+col] = t;
                xn2[grow*256+col] = (bf16)((t-mean)*rstd*n2w[col] + n2b[col]);
            }
        }
    }
}

// ---------------------------------------------------------------------------
// fused MLP v7: M=128, 1024 threads (16 waves, 4/SIMD), 4 sub-passes of 256
// hidden. v4's 2-barrier dataflow; dup-free 1 KB coalesced weight loads.
// LDS = 64 KB sA + 64 KB sH = 128 KB, 1 block/CU but 16 waves.
// ---------------------------------------------------------------------------
__global__ __launch_bounds__(1024, 4) void k_mlp(
    const bf16* __restrict__ xn2, const bf16* __restrict__ w12f,
    const float* __restrict__ fb12, const bf16* __restrict__ w2f,
    const float* __restrict__ fb2, float* __restrict__ out)
{
    __shared__ bf16 sA[8*128*32];   // 64 KB: [ks][128 tok][32] swizzled acts
    __shared__ bf16 sH[128*256];    // 64 KB: [tok][256 hid] XOR-swizzled
    const int tid = threadIdx.x, wid = tid>>6, l = tid&63;
    const int l16 = l&15, lg = l>>4;
    const size_t m0 = (size_t)blockIdx.x << 7;
    const int srow = l>>2;
    const int gk = ((l&3) ^ ((l>>3)&3)) << 3;
    // stage: wave wid -> ks = wid>>1, row-groups (wid&1)*4 + j
    {
        const int ks = wid >> 1;
        #pragma unroll
        for (int j=0;j<4;++j) {
            const int r16 = (wid&1)*4 + j;
            gl16(xn2 + (m0 + r16*16 + srow)*256 + ks*32 + gk,
                 &sA[(ks*128 + r16*16)*32]);
        }
    }
    const int slot = lg ^ ((l16>>1)&3);
    const int hloc = wid*16 + lg*4;          // hidden within 256-chunk
    f32x4 acc2[8] = {};
    __syncthreads();

    for (int sp = 0; sp < 4; ++sp) {
        // ---- GEMM1 (swapped): wave owns 16 hidden rows over 128 tokens ----
        const bf16* pg = w12f + (size_t)(sp*16 + wid) * 8 * 512;        // gate
        const bf16* pf = w12f + (size_t)(sp*16 + wid + 64) * 8 * 512;   // feat
        f32x4 ag[8] = {}, af[8] = {};
        #pragma unroll
        for (int ks=0; ks<8; ++ks) {
            bf16x8 wg = *(const bf16x8*)(pg + ks*512 + l*8);
            bf16x8 wf = *(const bf16x8*)(pf + ks*512 + l*8);
            #pragma unroll
            for (int m=0;m<8;++m) {
                bf16x8 av = *(const bf16x8*)&sA[(ks*128 + m*16 + l16)*32 + slot*8];
                ag[m] = mfma16(wg, av, ag[m]);
                af[m] = mfma16(wf, av, af[m]);
            }
        }
        float4 bg4 = *(const float4*)(fb12 + sp*256 + hloc);
        float4 bf4 = *(const float4*)(fb12 + 1024 + sp*256 + hloc);
        __syncthreads();   // previous sub-pass GEMM2 done reading sH
        #pragma unroll
        for (int m=0;m<8;++m) {
            const int tok = m*16 + l16;
            float g0 = ag[m][0]+bg4.x, g1 = ag[m][1]+bg4.y;
            float g2 = ag[m][2]+bg4.z, g3 = ag[m][3]+bg4.w;
            float h0 = g0*__builtin_amdgcn_rcpf(1.f+__expf(-g0))*(af[m][0]+bf4.x);
            float h1 = g1*__builtin_amdgcn_rcpf(1.f+__expf(-g1))*(af[m][1]+bf4.y);
            float h2 = g2*__builtin_amdgcn_rcpf(1.f+__expf(-g2))*(af[m][2]+bf4.z);
            float h3 = g3*__builtin_amdgcn_rcpf(1.f+__expf(-g3))*(af[m][3]+bf4.w);
            st_bf4(&sH[tok*256 + (hloc ^ ((tok&7)<<3))], h0, h1, h2, h3);
        }
        // ---- w2 prefetch (independent of sH) ----
        bf16x8 bb[8];
        #pragma unroll
        for (int c=0;c<8;++c)
            bb[c] = *(const bf16x8*)(w2f + (size_t)(wid*32 + sp*8 + c)*64*8 + l*8);
        __syncthreads();   // sH ready
        // ---- GEMM2: wave owns out cols wid*16..+15, K = this 256-hid slice
        #pragma unroll
        for (int c=0;c<8;++c) {
            #pragma unroll
            for (int m=0;m<8;++m) {
                const int tok = m*16 + l16;
                bf16x8 ah = *(const bf16x8*)&sH[tok*256 + ((c*32 + lg*8) ^ ((tok&7)<<3))];
                acc2[m] = mfma16(ah, bb[c], acc2[m]);
            }
        }
    }
    const int col = wid*16 + l16;
    const float bv = fb2[col];
    #pragma unroll
    for (int m=0;m<8;++m)
        #pragma unroll
        for (int r=0;r<4;++r) {
            const size_t idx = (m0 + m*16 + lg*4 + r)*256 + col;
            out[idx] += acc2[m][r] + bv;
        }
}

// ---------------------------------------------------------------------------
extern "C" void kernel_launch(void* const* d_in, const int* in_sizes, int n_in,
                              void* d_out, int out_size, void* d_ws, size_t ws_size,
                              hipStream_t stream) {
    const float* x      = (const float*)d_in[0];
    const float* n1w    = (const float*)d_in[1];
    const float* n1b    = (const float*)d_in[2];
    const float* qkvw   = (const float*)d_in[3];
    const float* qkvb   = (const float*)d_in[4];
    const float* projw  = (const float*)d_in[5];
    const float* projb  = (const float*)d_in[6];
    const float* rpb    = (const float*)d_in[7];
    const float* n2w    = (const float*)d_in[8];
    const float* n2b    = (const float*)d_in[9];
    const float* fc12w  = (const float*)d_in[10];
    const float* fc12b  = (const float*)d_in[11];
    const float* fc2w   = (const float*)d_in[12];
    const float* fc2b   = (const float*)d_in[13];
    float* out = (float*)d_out;

    char* ws = (char*)d_ws;
    bf16* wb       = (bf16*)ws;                        // 2 MiB converted weights
    bf16* qkvw_bf  = wb;
    bf16* projw_bf = wb + 196608;
    bf16* w12f_bf  = wb + 262144;
    bf16* w2f_bf   = wb + 786432;
    float* biasTab = (float*)(ws + 2097152);           // 512 KiB
    bf16* Qb  = (bf16*)(ws + 2621440);                 // 64 MiB
    bf16* Kb  = (bf16*)(ws + 69730304);                // 64 MiB
    bf16* Vt  = (bf16*)(ws + 136839168);               // 64 MiB (V transposed)
    bf16* xn1 = (bf16*)(ws + 203948032);               // 64 MiB
    bf16* xn2 = (bf16*)(ws + 203948032);               // over xn1 (dead after qkv)

    k_cvtw<<<512, 256, 0, stream>>>(qkvw, projw, fc12w, fc2w, wb);
    k_mkbias<<<512, 256, 0, stream>>>(rpb, biasTab);
    k_ln_win<<<32768, 256, 0, stream>>>(x, n1w, n1b, xn1);
    k_qkv<<<dim3(6, 1024), 256, 0, stream>>>(xn1, qkvw_bf, qkvb, Qb, Kb, Vt);
    k_attnproj<<<2048, 256, 0, stream>>>(Qb, Kb, Vt, biasTab, projw_bf, projb,
                                         x, n2w, n2b, out, xn2);
    k_mlp<<<1024, 1024, 0, stream>>>(xn2, w12f_bf, fc12b, w2f_bf, fc2b, out);
}

// Round 10
// 720.287 us; speedup vs baseline: 1.2302x; 1.2302x over previous
//
#include <hip/hip_runtime.h>
#include <hip/hip_bf16.h>
#include <stdint.h>

typedef __bf16 bf16;
typedef __bf16 bf16x4 __attribute__((ext_vector_type(4)));
typedef __bf16 bf16x8 __attribute__((ext_vector_type(8)));
typedef float  f32x4  __attribute__((ext_vector_type(4)));
typedef unsigned int u32;

__device__ __forceinline__ f32x4 mfma16(bf16x8 a, bf16x8 b, f32x4 c) {
    return __builtin_amdgcn_mfma_f32_16x16x32_bf16(a, b, c, 0, 0, 0);
}
__device__ __forceinline__ void st_bf4(bf16* p, float a, float b, float c, float d) {
    bf16x4 v = { (bf16)a, (bf16)b, (bf16)c, (bf16)d };
    *(bf16x4*)p = v;
}
// async global->LDS, 16B per lane; LDS dest = wave-uniform base + lane*16
__device__ __forceinline__ void gl16(const bf16* g, bf16* l) {
    __builtin_amdgcn_global_load_lds(
        (const __attribute__((address_space(1))) u32*)g,
        (__attribute__((address_space(3))) u32*)l, 16, 0, 0);
}

// ---------------------------------------------------------------------------
// weights f32 -> bf16.  qkvw/projw linear; fc12w/fc2w permuted into
// per-wave-fragment order so one wave load = 1 KB contiguous.
// ---------------------------------------------------------------------------
__global__ __launch_bounds__(256) void k_cvtw(
    const float* __restrict__ qkvw, const float* __restrict__ projw,
    const float* __restrict__ f12w, const float* __restrict__ f2w,
    bf16* __restrict__ wb)
{
    const int i = blockIdx.x * 256 + threadIdx.x;   // one 8-elem chunk
    const size_t doff = (size_t)i * 8;
    const float* src; size_t soff;
    if (i < 24576) {            // qkv linear (196608 elems)
        src = qkvw; soff = doff;
    } else if (i < 32768) {     // proj linear (65536)
        src = projw; soff = doff - 196608;
    } else if (i < 98304) {     // w12f permuted (524288)
        const int i3 = i - 32768;
        const int hrow16 = i3 >> 9, ks = (i3 >> 6) & 7, l = i3 & 63;
        src = f12w;
        soff = (size_t)(hrow16*16 + (l&15))*256 + ks*32 + (l>>4)*8;
    } else {                    // w2f permuted (262144)
        const int i4 = i - 98304;
        const int ob = i4 >> 11, kc = (i4 >> 6) & 31, l = i4 & 63;
        src = f2w;
        soff = (size_t)(ob*16 + (l&15))*1024 + kc*32 + (l>>4)*8;
    }
    float4 a = *(const float4*)(src + soff);
    float4 b = *(const float4*)(src + soff + 4);
    bf16x8 v = { (bf16)a.x,(bf16)a.y,(bf16)a.z,(bf16)a.w,
                 (bf16)b.x,(bf16)b.y,(bf16)b.z,(bf16)b.w };
    *(bf16x8*)(wb + doff) = v;
}

// ---------------------------------------------------------------------------
// bias+mask table: tab[type][h][m(key)][n(query)], 4*8*64*64 = 131072 f32
// ---------------------------------------------------------------------------
__global__ __launch_bounds__(256) void k_mkbias(
    const float* __restrict__ rpb, float* __restrict__ tab)
{
    const int idx = blockIdx.x * 256 + threadIdx.x;
    const int type = idx >> 15, h = (idx >> 12) & 7, m = (idx >> 6) & 63, n = idx & 63;
    const int mr = m >> 3, mc = m & 7, nr = n >> 3, nc = n & 7;
    float bv = rpb[((nr - mr + 7) * 15 + (nc - mc + 7)) * 8 + h];
    const int ter = type >> 1, tec = type & 1;
    const int hm = ter ? ((mr < 4) ? 1 : 2) : 0;
    const int wm = tec ? ((mc < 4) ? 1 : 2) : 0;
    const int hn = ter ? ((nr < 4) ? 1 : 2) : 0;
    const int wn = tec ? ((nc < 4) ? 1 : 2) : 0;
    if (hm != hn || wm != wn) bv -= 100.f;
    tab[idx] = bv;
}

// ---------------------------------------------------------------------------
// LN1 + window gather: output rows in window order (b,win,tok)
// ---------------------------------------------------------------------------
__global__ __launch_bounds__(256) void k_ln_win(
    const float* __restrict__ in, const float* __restrict__ gw_,
    const float* __restrict__ gb_, bf16* __restrict__ o)
{
    const int tid = threadIdx.x;
    const int wv = tid >> 6, ln = tid & 63;
    const size_t drow = (size_t)blockIdx.x * 4 + wv;
    const int b = drow >> 12, win = (drow >> 6) & 63, tok = drow & 63;
    const int wr = win >> 3, wc = win & 7, tr = tok >> 3, tc = tok & 7;
    const int hs = (wr * 8 + tr + 4) & 63, vs = (wc * 8 + tc + 4) & 63;
    const size_t srow = ((size_t)b << 12) | (hs << 6) | vs;
    const float* src = in + srow * 256;
    float4 v = *(const float4*)(src + ln * 4);
    float s = v.x + v.y + v.z + v.w;
    float q = v.x*v.x + v.y*v.y + v.z*v.z + v.w*v.w;
    #pragma unroll
    for (int ofs = 32; ofs; ofs >>= 1) { s += __shfl_xor(s, ofs); q += __shfl_xor(q, ofs); }
    const float mean = s * (1.0f/256.0f);
    const float var  = q * (1.0f/256.0f) - mean * mean;
    const float rstd = rsqrtf(var + 1e-5f);
    float4 gw = *(const float4*)(gw_ + ln*4);
    float4 gb = *(const float4*)(gb_ + ln*4);
    st_bf4(o + drow*256 + ln*4,
           (v.x-mean)*rstd*gw.x + gb.x, (v.y-mean)*rstd*gw.y + gb.y,
           (v.z-mean)*rstd*gw.z + gb.z, (v.w-mean)*rstd*gw.w + gb.w);
}

// ---------------------------------------------------------------------------
// QKV GEMM (window-ordered rows): Q/K linear window-major; V computed with
// SWAPPED mfma so the epilogue writes V^T [win][chan][tok] coalesced.
// Grid (6, 1024): N-blocks sharing an A-tile are dispatch-adjacent (L2 reuse).
// ---------------------------------------------------------------------------
__global__ __launch_bounds__(256) void k_qkv(
    const bf16* __restrict__ A, const bf16* __restrict__ Bw,
    const float* __restrict__ qkvb,
    bf16* __restrict__ Qb, bf16* __restrict__ Kb, bf16* __restrict__ Vt)
{
    __shared__ bf16 sA[128*32];
    __shared__ bf16 sB[128*32];
    const int tid = threadIdx.x, w = tid>>6, l = tid&63;
    const int l16 = l&15, lg = l>>4;
    const int wm = w>>1, wn = w&1;
    const int m0 = blockIdx.y<<7, n0 = blockIdx.x<<7;
    const bool vseg = (n0 >= 512);
    const int srow = l>>2;
    const int gk = ((l&3) ^ ((l>>3)&3)) << 3;
    const bf16* gA0 = A + (size_t)(m0 + w*32 + srow)*256 + gk;
    const bf16* gA1 = gA0 + 16*256;
    const bf16* gB0 = Bw + (size_t)(n0 + w*32 + srow)*256 + gk;
    const bf16* gB1 = gB0 + 16*256;
    bf16* lA0 = &sA[(w*32)*32];
    bf16* lA1 = &sA[(w*32+16)*32];
    bf16* lB0 = &sB[(w*32)*32];
    bf16* lB1 = &sB[(w*32+16)*32];
    const int slot = lg ^ ((l16>>1)&3);
    int adA[4], adB[4];
    #pragma unroll
    for (int i=0;i<4;++i) {
        adA[i] = (wm*64 + i*16 + l16)*32 + slot*8;
        adB[i] = (wn*64 + i*16 + l16)*32 + slot*8;
    }
    f32x4 acc[4][4] = {};
    for (int ks = 0; ks < 8; ++ks) {
        gl16(gA0 + ks*32, lA0); gl16(gA1 + ks*32, lA1);
        gl16(gB0 + ks*32, lB0); gl16(gB1 + ks*32, lB1);
        __syncthreads();
        bf16x8 av[4], bv[4];
        #pragma unroll
        for (int i=0;i<4;++i) { av[i] = *(const bf16x8*)&sA[adA[i]]; bv[i] = *(const bf16x8*)&sB[adB[i]]; }
        if (!vseg) {
            #pragma unroll
            for (int mi=0;mi<4;++mi)
                #pragma unroll
                for (int ni=0;ni<4;++ni)
                    acc[mi][ni] = mfma16(av[mi], bv[ni], acc[mi][ni]);
        } else {
            #pragma unroll
            for (int mi=0;mi<4;++mi)
                #pragma unroll
                for (int ni=0;ni<4;++ni)
                    acc[mi][ni] = mfma16(bv[ni], av[mi], acc[mi][ni]);
        }
        __syncthreads();
    }
    if (!vseg) {
        #pragma unroll
        for (int ni=0;ni<4;++ni) {
            const int cg = n0 + wn*64 + ni*16 + l16;
            const int seg = cg >> 8, cs = cg & 255;
            bf16* dst = (seg==0) ? Qb : Kb;
            const float mul = (seg==0) ? 0.1767766952966369f : 1.0f;
            const float bias = qkvb[cg];
            #pragma unroll
            for (int mi=0;mi<4;++mi) {
                const int row = m0 + wm*64 + mi*16 + lg*4;
                #pragma unroll
                for (int r=0;r<4;++r)
                    dst[(size_t)(row+r)*256 + cs] = (bf16)((acc[mi][ni][r] + bias)*mul);
            }
        }
    } else {
        const int winb = (m0 >> 6) + wm;
        #pragma unroll
        for (int ni=0;ni<4;++ni) {
            const int ch0 = (n0 - 512) + wn*64 + ni*16 + lg*4;
            const float4 b4 = *(const float4*)(qkvb + 512 + ch0);
            const float barr[4] = { b4.x, b4.y, b4.z, b4.w };
            #pragma unroll
            for (int mi=0;mi<4;++mi) {
                const int tok = mi*16 + l16;
                #pragma unroll
                for (int r=0;r<4;++r)
                    Vt[(size_t)winb*16384 + (size_t)(ch0+r)*64 + tok] =
                        (bf16)(acc[mi][ni][r] + barr[r]);
            }
        }
    }
}

// ---------------------------------------------------------------------------
// window attention v3: NO K/V LDS staging, NO barriers. K/V^T/bias frags read
// straight from global (L1/L2-backed, 4x wave reuse). Only sP (9 KB) in LDS.
// ---------------------------------------------------------------------------
__global__ __launch_bounds__(256) void k_attn(
    const bf16* __restrict__ Qb, const bf16* __restrict__ Kb,
    const bf16* __restrict__ Vt, const float* __restrict__ biasTab,
    bf16* __restrict__ ao)
{
    __shared__ bf16 sP[64][72];
    const int tid = threadIdx.x;
    const int wv = tid>>6, l = tid&63, l16 = l&15, lg = l>>4;
    const int win = blockIdx.x, ww = win&63;
    const int type = (((ww>>3)==7)?2:0) | (((ww&7)==7)?1:0);

    const bf16* Kw = Kb + (size_t)win*64*256;
    const bf16* Vw = Vt + (size_t)win*16384;

    const size_t qoff = ((size_t)win*64 + wv*16 + l16)*256 + lg*8;
    bf16x8 qf[8];
    #pragma unroll
    for (int h=0;h<8;++h) qf[h] = *(const bf16x8*)(Qb + qoff + h*32);

    bf16x8 kb[4];
    #pragma unroll
    for (int nt=0;nt<4;++nt)
        kb[nt] = *(const bf16x8*)(Kw + (size_t)(nt*16+l16)*256 + lg*8);

    const float* tb0 = biasTab + ((size_t)type<<15) + wv*16 + lg*4;

    for (int h=0; h<8; ++h) {
        const float* tb = tb0 + (h<<12);
        f32x4 at[4];
        #pragma unroll
        for (int nt=0;nt<4;++nt) {
            f32x4 bias4 = *(const f32x4*)(tb + (nt*16 + l16)*64);
            at[nt] = mfma16(qf[h], kb[nt], bias4);
        }
        if (h < 7) {   // prefetch next head's K under the softmax
            #pragma unroll
            for (int nt=0;nt<4;++nt)
                kb[nt] = *(const bf16x8*)(Kw + (size_t)(nt*16+l16)*256 + (h+1)*32 + lg*8);
        }
        #pragma unroll
        for (int r=0;r<4;++r) {
            float mx = fmaxf(fmaxf(at[0][r],at[1][r]), fmaxf(at[2][r],at[3][r]));
            #pragma unroll
            for (int ofs=8;ofs;ofs>>=1) mx = fmaxf(mx, __shfl_xor(mx,ofs));
            float e0 = __expf(at[0][r]-mx), e1 = __expf(at[1][r]-mx);
            float e2 = __expf(at[2][r]-mx), e3 = __expf(at[3][r]-mx);
            float sm = e0+e1+e2+e3;
            #pragma unroll
            for (int ofs=8;ofs;ofs>>=1) sm += __shfl_xor(sm,ofs);
            const float inv = 1.0f/sm;
            const int n = wv*16 + lg*4 + r;
            sP[n][ 0+l16] = (bf16)(e0*inv);
            sP[n][16+l16] = (bf16)(e1*inv);
            sP[n][32+l16] = (bf16)(e2*inv);
            sP[n][48+l16] = (bf16)(e3*inv);
        }
        #pragma unroll
        for (int nt=0;nt<2;++nt) {
            f32x4 o = {};
            #pragma unroll
            for (int ks=0;ks<2;++ks) {
                bf16x8 pa = *(const bf16x8*)&sP[wv*16+l16][ks*32+lg*8];
                bf16x8 vb = *(const bf16x8*)(Vw + (size_t)(h*32+nt*16+l16)*64 + ks*32 + lg*8);
                o = mfma16(pa, vb, o);
            }
            #pragma unroll
            for (int r=0;r<4;++r)
                ao[((size_t)win*64 + wv*16 + lg*4 + r)*256 + h*32 + nt*16 + l16] = (bf16)o[r];
        }
    }
}

// ---------------------------------------------------------------------------
// proj GEMM (128x256, K=256) + reverse-shift scatter + residual + LN2 fused
// ---------------------------------------------------------------------------
__global__ __launch_bounds__(256) void k_proj(
    const bf16* __restrict__ ao, const bf16* __restrict__ Bw,
    const float* __restrict__ projb, const float* __restrict__ x,
    const float* __restrict__ n2w, const float* __restrict__ n2b,
    float* __restrict__ out, bf16* __restrict__ xn2)
{
    __shared__ bf16 sA[128*32];
    __shared__ bf16 sB[256*32];
    const int tid = threadIdx.x, w = tid>>6, l = tid&63;
    const int l16 = l&15, lg = l>>4;
    const int m0 = blockIdx.x<<7;
    const int srow = l>>2;
    const int gk = ((l&3) ^ ((l>>3)&3)) << 3;
    const bf16* gA0 = ao + (size_t)(m0 + w*32 + srow)*256 + gk;
    const bf16* gA1 = gA0 + 16*256;
    const bf16* gB0 = Bw + (size_t)(w*64 + srow)*256 + gk;
    bf16* lA0 = &sA[(w*32)*32];
    bf16* lA1 = &sA[(w*32+16)*32];
    bf16* lB0 = &sB[(w*64)*32];
    const int slot = lg ^ ((l16>>1)&3);
    const int adA0 = (w*32 + l16)*32 + slot*8;
    const int adA1 = (w*32+16 + l16)*32 + slot*8;
    f32x4 acc[2][16] = {};
    for (int ks=0; ks<8; ++ks) {
        gl16(gA0 + ks*32, lA0); gl16(gA1 + ks*32, lA1);
        #pragma unroll
        for (int i=0;i<4;++i)
            gl16(gB0 + i*16*256 + ks*32, lB0 + i*16*32);
        __syncthreads();
        bf16x8 a0 = *(const bf16x8*)&sA[adA0];
        bf16x8 a1 = *(const bf16x8*)&sA[adA1];
        #pragma unroll
        for (int nj=0;nj<16;++nj) {
            bf16x8 bvv = *(const bf16x8*)&sB[(nj*16 + l16)*32 + slot*8];
            acc[0][nj] = mfma16(a0, bvv, acc[0][nj]);
            acc[1][nj] = mfma16(a1, bvv, acc[1][nj]);
        }
        __syncthreads();
    }
    #pragma unroll
    for (int mi=0;mi<2;++mi) {
        #pragma unroll
        for (int rr=0;rr<4;++rr) {
            const int rgw = m0 + w*32 + mi*16 + lg*4 + rr;
            const int win = rgw>>6, tok = rgw&63;
            const int bb = win>>6, wwi = win&63;
            const int wr = wwi>>3, wc = wwi&7, tr = tok>>3, tc = tok&7;
            const int hs = (wr*8+tr+4)&63, vs = (wc*8+tc+4)&63;
            const size_t grow = ((size_t)bb<<12) + (hs<<6) + vs;
            float vals[16]; float s=0.f, s2=0.f;
            #pragma unroll
            for (int nj=0;nj<16;++nj) {
                const int col = nj*16 + l16;
                const float t = acc[mi][nj][rr] + projb[col] + x[grow*256 + col];
                vals[nj] = t; s += t; s2 += t*t;
            }
            #pragma unroll
            for (int ofs=8;ofs;ofs>>=1){ s += __shfl_xor(s,ofs); s2 += __shfl_xor(s2,ofs); }
            const float mean = s*(1.f/256.f);
            const float rstd = rsqrtf(s2*(1.f/256.f) - mean*mean + 1e-5f);
            #pragma unroll
            for (int nj=0;nj<16;++nj) {
                const int col = nj*16 + l16;
                out[grow*256+col] = vals[nj];
                xn2[grow*256+col] = (bf16)((vals[nj]-mean)*rstd*n2w[col] + n2b[col]);
            }
        }
    }
}

// ---------------------------------------------------------------------------
// fused MLP v4 + setprio: M=128 tokens, 512 threads (8 waves), 8 sub-passes
// of 128 hidden. Dup-free 1 KB coalesced weight loads (permuted w12f/w2f).
// s_setprio(1) wraps the two MFMA clusters (T5; phase-split regime).
// LDS = 64 KB sA + 32 KB sH = 96 KB -> 1 block/CU.
// ---------------------------------------------------------------------------
__global__ __launch_bounds__(512, 2) void k_mlp(
    const bf16* __restrict__ xn2, const bf16* __restrict__ w12f,
    const float* __restrict__ fb12, const bf16* __restrict__ w2f,
    const float* __restrict__ fb2, float* __restrict__ out)
{
    __shared__ bf16 sA[8*128*32];   // 64 KB: [ks][128 tok][32] swizzled acts
    __shared__ bf16 sH[128*128];    // 32 KB: [tok][128 hid] XOR-swizzled
    const int tid = threadIdx.x, wid = tid>>6, l = tid&63;
    const int l16 = l&15, lg = l>>4;
    const size_t m0 = (size_t)blockIdx.x << 7;
    const int srow = l>>2;
    const int gk = ((l&3) ^ ((l>>3)&3)) << 3;
    const bf16* gA = xn2 + (m0 + wid*16 + srow)*256 + gk;
    #pragma unroll
    for (int ks=0; ks<8; ++ks)
        gl16(gA + ks*32, &sA[(ks*128 + wid*16)*32]);

    const int slot = lg ^ ((l16>>1)&3);
    f32x4 acc2[8][2] = {};
    __syncthreads();

    for (int sp = 0; sp < 8; ++sp) {
        const bf16* pg = w12f + ((size_t)(sp*8 + wid) * 8) * 512;       // gate
        const bf16* pf = w12f + ((size_t)(sp*8 + wid + 64) * 8) * 512;  // feat
        f32x4 ag[8] = {}, af[8] = {};
        __builtin_amdgcn_s_setprio(1);
        #pragma unroll
        for (int ks=0; ks<8; ++ks) {
            bf16x8 wg = *(const bf16x8*)(pg + ks*512 + l*8);
            bf16x8 wf = *(const bf16x8*)(pf + ks*512 + l*8);
            #pragma unroll
            for (int m=0;m<8;++m) {
                bf16x8 av = *(const bf16x8*)&sA[(ks*128 + m*16 + l16)*32 + slot*8];
                ag[m] = mfma16(wg, av, ag[m]);
                af[m] = mfma16(wf, av, af[m]);
            }
        }
        __builtin_amdgcn_s_setprio(0);
        const int hloc = wid*16 + lg*4;
        float4 bg4 = *(const float4*)(fb12 + sp*128 + hloc);
        float4 bf4 = *(const float4*)(fb12 + 1024 + sp*128 + hloc);
        __syncthreads();   // previous sub-pass GEMM2 done reading sH
        #pragma unroll
        for (int m=0;m<8;++m) {
            const int tok = m*16 + l16;
            float g0 = ag[m][0]+bg4.x, g1 = ag[m][1]+bg4.y;
            float g2 = ag[m][2]+bg4.z, g3 = ag[m][3]+bg4.w;
            float h0 = g0*__builtin_amdgcn_rcpf(1.f+__expf(-g0))*(af[m][0]+bf4.x);
            float h1 = g1*__builtin_amdgcn_rcpf(1.f+__expf(-g1))*(af[m][1]+bf4.y);
            float h2 = g2*__builtin_amdgcn_rcpf(1.f+__expf(-g2))*(af[m][2]+bf4.z);
            float h3 = g3*__builtin_amdgcn_rcpf(1.f+__expf(-g3))*(af[m][3]+bf4.w);
            st_bf4(&sH[tok*128 + (hloc ^ ((tok&7)<<3))], h0, h1, h2, h3);
        }
        bf16x8 bb[4][2];
        #pragma unroll
        for (int c=0;c<4;++c)
            #pragma unroll
            for (int n=0;n<2;++n) {
                const int ob = wid*2 + n, kc = sp*4 + c;
                bb[c][n] = *(const bf16x8*)(w2f + ((size_t)(ob*32 + kc)*64 + l)*8);
            }
        __syncthreads();   // sH ready
        __builtin_amdgcn_s_setprio(1);
        #pragma unroll
        for (int c=0;c<4;++c) {
            bf16x8 ah[8];
            #pragma unroll
            for (int m=0;m<8;++m) {
                const int tok = m*16 + l16;
                ah[m] = *(const bf16x8*)&sH[tok*128 + ((c*32 + lg*8) ^ ((tok&7)<<3))];
            }
            #pragma unroll
            for (int n=0;n<2;++n)
                #pragma unroll
                for (int m=0;m<8;++m)
                    acc2[m][n] = mfma16(ah[m], bb[c][n], acc2[m][n]);
        }
        __builtin_amdgcn_s_setprio(0);
    }
    #pragma unroll
    for (int n=0;n<2;++n) {
        const int col = wid*32 + n*16 + l16;
        const float bv = fb2[col];
        #pragma unroll
        for (int m=0;m<8;++m)
            #pragma unroll
            for (int r=0;r<4;++r) {
                const size_t idx = (m0 + m*16 + lg*4 + r)*256 + col;
                out[idx] += acc2[m][n][r] + bv;
            }
    }
}

// ---------------------------------------------------------------------------
extern "C" void kernel_launch(void* const* d_in, const int* in_sizes, int n_in,
                              void* d_out, int out_size, void* d_ws, size_t ws_size,
                              hipStream_t stream) {
    const float* x      = (const float*)d_in[0];
    const float* n1w    = (const float*)d_in[1];
    const float* n1b    = (const float*)d_in[2];
    const float* qkvw   = (const float*)d_in[3];
    const float* qkvb   = (const float*)d_in[4];
    const float* projw  = (const float*)d_in[5];
    const float* projb  = (const float*)d_in[6];
    const float* rpb    = (const float*)d_in[7];
    const float* n2w    = (const float*)d_in[8];
    const float* n2b    = (const float*)d_in[9];
    const float* fc12w  = (const float*)d_in[10];
    const float* fc12b  = (const float*)d_in[11];
    const float* fc2w   = (const float*)d_in[12];
    const float* fc2b   = (const float*)d_in[13];
    float* out = (float*)d_out;

    char* ws = (char*)d_ws;
    bf16* wb       = (bf16*)ws;                        // 2 MiB converted weights
    bf16* qkvw_bf  = wb;
    bf16* projw_bf = wb + 196608;
    bf16* w12f_bf  = wb + 262144;
    bf16* w2f_bf   = wb + 786432;
    float* biasTab = (float*)(ws + 2097152);           // 512 KiB
    bf16* Qb  = (bf16*)(ws + 2621440);                 // 64 MiB
    bf16* Kb  = (bf16*)(ws + 69730304);                // 64 MiB
    bf16* Vt  = (bf16*)(ws + 136839168);               // 64 MiB (V transposed)
    bf16* xn1 = (bf16*)(ws + 203948032);               // 64 MiB (reused as ao)
    bf16* ao  = (bf16*)(ws + 203948032);
    bf16* xn2 = (bf16*)(ws + 2621440);                 // over Qb (dead after attn)

    k_cvtw<<<512, 256, 0, stream>>>(qkvw, projw, fc12w, fc2w, wb);
    k_mkbias<<<512, 256, 0, stream>>>(rpb, biasTab);
    k_ln_win<<<32768, 256, 0, stream>>>(x, n1w, n1b, xn1);
    k_qkv<<<dim3(6, 1024), 256, 0, stream>>>(xn1, qkvw_bf, qkvb, Qb, Kb, Vt);
    k_attn<<<2048, 256, 0, stream>>>(Qb, Kb, Vt, biasTab, ao);
    k_proj<<<1024, 256, 0, stream>>>(ao, projw_bf, projb, x, n2w, n2b, out, xn2);
    k_mlp<<<1024, 512, 0, stream>>>(xn2, w12f_bf, fc12b, w2f_bf, fc2b, out);
}

// Round 11
// 709.691 us; speedup vs baseline: 1.2486x; 1.0149x over previous
//
#include <hip/hip_runtime.h>
#include <hip/hip_bf16.h>
#include <stdint.h>

typedef __bf16 bf16;
typedef __bf16 bf16x4 __attribute__((ext_vector_type(4)));
typedef __bf16 bf16x8 __attribute__((ext_vector_type(8)));
typedef float  f32x4  __attribute__((ext_vector_type(4)));
typedef unsigned int u32;

__device__ __forceinline__ f32x4 mfma16(bf16x8 a, bf16x8 b, f32x4 c) {
    return __builtin_amdgcn_mfma_f32_16x16x32_bf16(a, b, c, 0, 0, 0);
}
__device__ __forceinline__ void st_bf4(bf16* p, float a, float b, float c, float d) {
    bf16x4 v = { (bf16)a, (bf16)b, (bf16)c, (bf16)d };
    *(bf16x4*)p = v;
}
// async global->LDS, 16B per lane; LDS dest = wave-uniform base + lane*16
__device__ __forceinline__ void gl16(const bf16* g, bf16* l) {
    __builtin_amdgcn_global_load_lds(
        (const __attribute__((address_space(1))) u32*)g,
        (__attribute__((address_space(3))) u32*)l, 16, 0, 0);
}

// ---------------------------------------------------------------------------
// weights f32 -> bf16.  qkvw/projw linear; fc12w/fc2w permuted into
// per-wave-fragment order so one wave load = 1 KB contiguous.
// ---------------------------------------------------------------------------
__global__ __launch_bounds__(256) void k_cvtw(
    const float* __restrict__ qkvw, const float* __restrict__ projw,
    const float* __restrict__ f12w, const float* __restrict__ f2w,
    bf16* __restrict__ wb)
{
    const int i = blockIdx.x * 256 + threadIdx.x;   // one 8-elem chunk
    const size_t doff = (size_t)i * 8;
    const float* src; size_t soff;
    if (i < 24576) {            // qkv linear (196608 elems)
        src = qkvw; soff = doff;
    } else if (i < 32768) {     // proj linear (65536)
        src = projw; soff = doff - 196608;
    } else if (i < 98304) {     // w12f permuted (524288)
        const int i3 = i - 32768;
        const int hrow16 = i3 >> 9, ks = (i3 >> 6) & 7, l = i3 & 63;
        src = f12w;
        soff = (size_t)(hrow16*16 + (l&15))*256 + ks*32 + (l>>4)*8;
    } else {                    // w2f permuted (262144)
        const int i4 = i - 98304;
        const int ob = i4 >> 11, kc = (i4 >> 6) & 31, l = i4 & 63;
        src = f2w;
        soff = (size_t)(ob*16 + (l&15))*1024 + kc*32 + (l>>4)*8;
    }
    float4 a = *(const float4*)(src + soff);
    float4 b = *(const float4*)(src + soff + 4);
    bf16x8 v = { (bf16)a.x,(bf16)a.y,(bf16)a.z,(bf16)a.w,
                 (bf16)b.x,(bf16)b.y,(bf16)b.z,(bf16)b.w };
    *(bf16x8*)(wb + doff) = v;
}

// ---------------------------------------------------------------------------
// bias+mask table: tab[type][h][m(key)][n(query)], 4*8*64*64 = 131072 f32
// ---------------------------------------------------------------------------
__global__ __launch_bounds__(256) void k_mkbias(
    const float* __restrict__ rpb, float* __restrict__ tab)
{
    const int idx = blockIdx.x * 256 + threadIdx.x;
    const int type = idx >> 15, h = (idx >> 12) & 7, m = (idx >> 6) & 63, n = idx & 63;
    const int mr = m >> 3, mc = m & 7, nr = n >> 3, nc = n & 7;
    float bv = rpb[((nr - mr + 7) * 15 + (nc - mc + 7)) * 8 + h];
    const int ter = type >> 1, tec = type & 1;
    const int hm = ter ? ((mr < 4) ? 1 : 2) : 0;
    const int wm = tec ? ((mc < 4) ? 1 : 2) : 0;
    const int hn = ter ? ((nr < 4) ? 1 : 2) : 0;
    const int wn = tec ? ((nc < 4) ? 1 : 2) : 0;
    if (hm != hn || wm != wn) bv -= 100.f;
    tab[idx] = bv;
}

// ---------------------------------------------------------------------------
// LN1 + window gather: output rows in window order (b,win,tok)
// ---------------------------------------------------------------------------
__global__ __launch_bounds__(256) void k_ln_win(
    const float* __restrict__ in, const float* __restrict__ gw_,
    const float* __restrict__ gb_, bf16* __restrict__ o)
{
    const int tid = threadIdx.x;
    const int wv = tid >> 6, ln = tid & 63;
    const size_t drow = (size_t)blockIdx.x * 4 + wv;
    const int b = drow >> 12, win = (drow >> 6) & 63, tok = drow & 63;
    const int wr = win >> 3, wc = win & 7, tr = tok >> 3, tc = tok & 7;
    const int hs = (wr * 8 + tr + 4) & 63, vs = (wc * 8 + tc + 4) & 63;
    const size_t srow = ((size_t)b << 12) | (hs << 6) | vs;
    const float* src = in + srow * 256;
    float4 v = *(const float4*)(src + ln * 4);
    float s = v.x + v.y + v.z + v.w;
    float q = v.x*v.x + v.y*v.y + v.z*v.z + v.w*v.w;
    #pragma unroll
    for (int ofs = 32; ofs; ofs >>= 1) { s += __shfl_xor(s, ofs); q += __shfl_xor(q, ofs); }
    const float mean = s * (1.0f/256.0f);
    const float var  = q * (1.0f/256.0f) - mean * mean;
    const float rstd = rsqrtf(var + 1e-5f);
    float4 gw = *(const float4*)(gw_ + ln*4);
    float4 gb = *(const float4*)(gb_ + ln*4);
    st_bf4(o + drow*256 + ln*4,
           (v.x-mean)*rstd*gw.x + gb.x, (v.y-mean)*rstd*gw.y + gb.y,
           (v.z-mean)*rstd*gw.z + gb.z, (v.w-mean)*rstd*gw.w + gb.w);
}

// ---------------------------------------------------------------------------
// QKV GEMM (window-ordered rows): Q/K linear window-major; V computed with
// SWAPPED mfma so the epilogue writes V^T [win][chan][tok] coalesced.
// Grid (6, 1024): N-blocks sharing an A-tile are dispatch-adjacent (L2 reuse).
// ---------------------------------------------------------------------------
__global__ __launch_bounds__(256) void k_qkv(
    const bf16* __restrict__ A, const bf16* __restrict__ Bw,
    const float* __restrict__ qkvb,
    bf16* __restrict__ Qb, bf16* __restrict__ Kb, bf16* __restrict__ Vt)
{
    __shared__ bf16 sA[128*32];
    __shared__ bf16 sB[128*32];
    const int tid = threadIdx.x, w = tid>>6, l = tid&63;
    const int l16 = l&15, lg = l>>4;
    const int wm = w>>1, wn = w&1;
    const int m0 = blockIdx.y<<7, n0 = blockIdx.x<<7;
    const bool vseg = (n0 >= 512);
    const int srow = l>>2;
    const int gk = ((l&3) ^ ((l>>3)&3)) << 3;
    const bf16* gA0 = A + (size_t)(m0 + w*32 + srow)*256 + gk;
    const bf16* gA1 = gA0 + 16*256;
    const bf16* gB0 = Bw + (size_t)(n0 + w*32 + srow)*256 + gk;
    const bf16* gB1 = gB0 + 16*256;
    bf16* lA0 = &sA[(w*32)*32];
    bf16* lA1 = &sA[(w*32+16)*32];
    bf16* lB0 = &sB[(w*32)*32];
    bf16* lB1 = &sB[(w*32+16)*32];
    const int slot = lg ^ ((l16>>1)&3);
    int adA[4], adB[4];
    #pragma unroll
    for (int i=0;i<4;++i) {
        adA[i] = (wm*64 + i*16 + l16)*32 + slot*8;
        adB[i] = (wn*64 + i*16 + l16)*32 + slot*8;
    }
    f32x4 acc[4][4] = {};
    for (int ks = 0; ks < 8; ++ks) {
        gl16(gA0 + ks*32, lA0); gl16(gA1 + ks*32, lA1);
        gl16(gB0 + ks*32, lB0); gl16(gB1 + ks*32, lB1);
        __syncthreads();
        bf16x8 av[4], bv[4];
        #pragma unroll
        for (int i=0;i<4;++i) { av[i] = *(const bf16x8*)&sA[adA[i]]; bv[i] = *(const bf16x8*)&sB[adB[i]]; }
        if (!vseg) {
            #pragma unroll
            for (int mi=0;mi<4;++mi)
                #pragma unroll
                for (int ni=0;ni<4;++ni)
                    acc[mi][ni] = mfma16(av[mi], bv[ni], acc[mi][ni]);
        } else {
            #pragma unroll
            for (int mi=0;mi<4;++mi)
                #pragma unroll
                for (int ni=0;ni<4;++ni)
                    acc[mi][ni] = mfma16(bv[ni], av[mi], acc[mi][ni]);
        }
        __syncthreads();
    }
    if (!vseg) {
        #pragma unroll
        for (int ni=0;ni<4;++ni) {
            const int cg = n0 + wn*64 + ni*16 + l16;
            const int seg = cg >> 8, cs = cg & 255;
            bf16* dst = (seg==0) ? Qb : Kb;
            const float mul = (seg==0) ? 0.1767766952966369f : 1.0f;
            const float bias = qkvb[cg];
            #pragma unroll
            for (int mi=0;mi<4;++mi) {
                const int row = m0 + wm*64 + mi*16 + lg*4;
                #pragma unroll
                for (int r=0;r<4;++r)
                    dst[(size_t)(row+r)*256 + cs] = (bf16)((acc[mi][ni][r] + bias)*mul);
            }
        }
    } else {
        const int winb = (m0 >> 6) + wm;
        #pragma unroll
        for (int ni=0;ni<4;++ni) {
            const int ch0 = (n0 - 512) + wn*64 + ni*16 + lg*4;
            const float4 b4 = *(const float4*)(qkvb + 512 + ch0);
            const float barr[4] = { b4.x, b4.y, b4.z, b4.w };
            #pragma unroll
            for (int mi=0;mi<4;++mi) {
                const int tok = mi*16 + l16;
                #pragma unroll
                for (int r=0;r<4;++r)
                    Vt[(size_t)winb*16384 + (size_t)(ch0+r)*64 + tok] =
                        (bf16)(acc[mi][ni][r] + barr[r]);
            }
        }
    }
}

// ---------------------------------------------------------------------------
// window attention v4: no K/V LDS staging, no barriers; K/V^T/bias from L2.
// Output buffered 2 heads at a time in sO2 (8.7 KB, wave-private rows) and
// flushed as coalesced uint2 stores (16 wide stores vs 64 scalar 2B stores).
// ---------------------------------------------------------------------------
__global__ __launch_bounds__(256) void k_attn(
    const bf16* __restrict__ Qb, const bf16* __restrict__ Kb,
    const bf16* __restrict__ Vt, const float* __restrict__ biasTab,
    bf16* __restrict__ ao)
{
    __shared__ bf16 sP[64][72];
    __shared__ bf16 sO2[64][68];
    const int tid = threadIdx.x;
    const int wv = tid>>6, l = tid&63, l16 = l&15, lg = l>>4;
    const int win = blockIdx.x, ww = win&63;
    const int type = (((ww>>3)==7)?2:0) | (((ww&7)==7)?1:0);

    const bf16* Kw = Kb + (size_t)win*64*256;
    const bf16* Vw = Vt + (size_t)win*16384;

    const size_t qoff = ((size_t)win*64 + wv*16 + l16)*256 + lg*8;
    bf16x8 qf[8];
    #pragma unroll
    for (int h=0;h<8;++h) qf[h] = *(const bf16x8*)(Qb + qoff + h*32);

    bf16x8 kb[4];
    #pragma unroll
    for (int nt=0;nt<4;++nt)
        kb[nt] = *(const bf16x8*)(Kw + (size_t)(nt*16+l16)*256 + lg*8);

    const float* tb0 = biasTab + ((size_t)type<<15) + wv*16 + lg*4;

    for (int h=0; h<8; ++h) {
        const float* tb = tb0 + (h<<12);
        f32x4 at[4];
        #pragma unroll
        for (int nt=0;nt<4;++nt) {
            f32x4 bias4 = *(const f32x4*)(tb + (nt*16 + l16)*64);
            at[nt] = mfma16(qf[h], kb[nt], bias4);
        }
        if (h < 7) {   // prefetch next head's K under the softmax
            #pragma unroll
            for (int nt=0;nt<4;++nt)
                kb[nt] = *(const bf16x8*)(Kw + (size_t)(nt*16+l16)*256 + (h+1)*32 + lg*8);
        }
        #pragma unroll
        for (int r=0;r<4;++r) {
            float mx = fmaxf(fmaxf(at[0][r],at[1][r]), fmaxf(at[2][r],at[3][r]));
            #pragma unroll
            for (int ofs=8;ofs;ofs>>=1) mx = fmaxf(mx, __shfl_xor(mx,ofs));
            float e0 = __expf(at[0][r]-mx), e1 = __expf(at[1][r]-mx);
            float e2 = __expf(at[2][r]-mx), e3 = __expf(at[3][r]-mx);
            float sm = e0+e1+e2+e3;
            #pragma unroll
            for (int ofs=8;ofs;ofs>>=1) sm += __shfl_xor(sm,ofs);
            const float inv = 1.0f/sm;
            const int n = wv*16 + lg*4 + r;
            sP[n][ 0+l16] = (bf16)(e0*inv);
            sP[n][16+l16] = (bf16)(e1*inv);
            sP[n][32+l16] = (bf16)(e2*inv);
            sP[n][48+l16] = (bf16)(e3*inv);
        }
        #pragma unroll
        for (int nt=0;nt<2;++nt) {
            f32x4 o = {};
            #pragma unroll
            for (int ks=0;ks<2;++ks) {
                bf16x8 pa = *(const bf16x8*)&sP[wv*16+l16][ks*32+lg*8];
                bf16x8 vb = *(const bf16x8*)(Vw + (size_t)(h*32+nt*16+l16)*64 + ks*32 + lg*8);
                o = mfma16(pa, vb, o);
            }
            #pragma unroll
            for (int r=0;r<4;++r)
                sO2[wv*16 + lg*4 + r][(h&1)*32 + nt*16 + l16] = (bf16)o[r];
        }
        if (h & 1) {   // flush heads h-1,h: coalesced 8B stores (same-wave rows)
            #pragma unroll
            for (int r=0;r<4;++r) {
                const int row = wv*16 + lg*4 + r;
                *(uint2*)(ao + ((size_t)win*64 + row)*256 + (h-1)*32 + l16*4) =
                    *(const uint2*)&sO2[row][l16*4];
            }
        }
    }
}

// ---------------------------------------------------------------------------
// proj GEMM (128x256, K=256) + reverse-shift scatter + residual + LN2 fused
// ---------------------------------------------------------------------------
__global__ __launch_bounds__(256) void k_proj(
    const bf16* __restrict__ ao, const bf16* __restrict__ Bw,
    const float* __restrict__ projb, const float* __restrict__ x,
    const float* __restrict__ n2w, const float* __restrict__ n2b,
    float* __restrict__ out, bf16* __restrict__ xn2)
{
    __shared__ bf16 sA[128*32];
    __shared__ bf16 sB[256*32];
    const int tid = threadIdx.x, w = tid>>6, l = tid&63;
    const int l16 = l&15, lg = l>>4;
    const int m0 = blockIdx.x<<7;
    const int srow = l>>2;
    const int gk = ((l&3) ^ ((l>>3)&3)) << 3;
    const bf16* gA0 = ao + (size_t)(m0 + w*32 + srow)*256 + gk;
    const bf16* gA1 = gA0 + 16*256;
    const bf16* gB0 = Bw + (size_t)(w*64 + srow)*256 + gk;
    bf16* lA0 = &sA[(w*32)*32];
    bf16* lA1 = &sA[(w*32+16)*32];
    bf16* lB0 = &sB[(w*64)*32];
    const int slot = lg ^ ((l16>>1)&3);
    const int adA0 = (w*32 + l16)*32 + slot*8;
    const int adA1 = (w*32+16 + l16)*32 + slot*8;
    f32x4 acc[2][16] = {};
    for (int ks=0; ks<8; ++ks) {
        gl16(gA0 + ks*32, lA0); gl16(gA1 + ks*32, lA1);
        #pragma unroll
        for (int i=0;i<4;++i)
            gl16(gB0 + i*16*256 + ks*32, lB0 + i*16*32);
        __syncthreads();
        bf16x8 a0 = *(const bf16x8*)&sA[adA0];
        bf16x8 a1 = *(const bf16x8*)&sA[adA1];
        #pragma unroll
        for (int nj=0;nj<16;++nj) {
            bf16x8 bvv = *(const bf16x8*)&sB[(nj*16 + l16)*32 + slot*8];
            acc[0][nj] = mfma16(a0, bvv, acc[0][nj]);
            acc[1][nj] = mfma16(a1, bvv, acc[1][nj]);
        }
        __syncthreads();
    }
    #pragma unroll
    for (int mi=0;mi<2;++mi) {
        #pragma unroll
        for (int rr=0;rr<4;++rr) {
            const int rgw = m0 + w*32 + mi*16 + lg*4 + rr;
            const int win = rgw>>6, tok = rgw&63;
            const int bb = win>>6, wwi = win&63;
            const int wr = wwi>>3, wc = wwi&7, tr = tok>>3, tc = tok&7;
            const int hs = (wr*8+tr+4)&63, vs = (wc*8+tc+4)&63;
            const size_t grow = ((size_t)bb<<12) + (hs<<6) + vs;
            float vals[16]; float s=0.f, s2=0.f;
            #pragma unroll
            for (int nj=0;nj<16;++nj) {
                const int col = nj*16 + l16;
                const float t = acc[mi][nj][rr] + projb[col] + x[grow*256 + col];
                vals[nj] = t; s += t; s2 += t*t;
            }
            #pragma unroll
            for (int ofs=8;ofs;ofs>>=1){ s += __shfl_xor(s,ofs); s2 += __shfl_xor(s2,ofs); }
            const float mean = s*(1.f/256.f);
            const float rstd = rsqrtf(s2*(1.f/256.f) - mean*mean + 1e-5f);
            #pragma unroll
            for (int nj=0;nj<16;++nj) {
                const int col = nj*16 + l16;
                out[grow*256+col] = vals[nj];
                xn2[grow*256+col] = (bf16)((vals[nj]-mean)*rstd*n2w[col] + n2b[col]);
            }
        }
    }
}

// ---------------------------------------------------------------------------
// fused MLP v4 (r7-measured 255 us): M=128 tokens, 512 threads (8 waves),
// 8 sub-passes of 128 hidden. Dup-free 1 KB coalesced weight loads.
// LDS = 64 KB sA + 32 KB sH = 96 KB -> 1 block/CU.
// ---------------------------------------------------------------------------
__global__ __launch_bounds__(512, 2) void k_mlp(
    const bf16* __restrict__ xn2, const bf16* __restrict__ w12f,
    const float* __restrict__ fb12, const bf16* __restrict__ w2f,
    const float* __restrict__ fb2, float* __restrict__ out)
{
    __shared__ bf16 sA[8*128*32];   // 64 KB: [ks][128 tok][32] swizzled acts
    __shared__ bf16 sH[128*128];    // 32 KB: [tok][128 hid] XOR-swizzled
    const int tid = threadIdx.x, wid = tid>>6, l = tid&63;
    const int l16 = l&15, lg = l>>4;
    const size_t m0 = (size_t)blockIdx.x << 7;
    const int srow = l>>2;
    const int gk = ((l&3) ^ ((l>>3)&3)) << 3;
    const bf16* gA = xn2 + (m0 + wid*16 + srow)*256 + gk;
    #pragma unroll
    for (int ks=0; ks<8; ++ks)
        gl16(gA + ks*32, &sA[(ks*128 + wid*16)*32]);

    const int slot = lg ^ ((l16>>1)&3);
    f32x4 acc2[8][2] = {};
    __syncthreads();

    for (int sp = 0; sp < 8; ++sp) {
        const bf16* pg = w12f + ((size_t)(sp*8 + wid) * 8) * 512;       // gate
        const bf16* pf = w12f + ((size_t)(sp*8 + wid + 64) * 8) * 512;  // feat
        f32x4 ag[8] = {}, af[8] = {};
        #pragma unroll
        for (int ks=0; ks<8; ++ks) {
            bf16x8 wg = *(const bf16x8*)(pg + ks*512 + l*8);
            bf16x8 wf = *(const bf16x8*)(pf + ks*512 + l*8);
            #pragma unroll
            for (int m=0;m<8;++m) {
                bf16x8 av = *(const bf16x8*)&sA[(ks*128 + m*16 + l16)*32 + slot*8];
                ag[m] = mfma16(wg, av, ag[m]);
                af[m] = mfma16(wf, av, af[m]);
            }
        }
        const int hloc = wid*16 + lg*4;
        float4 bg4 = *(const float4*)(fb12 + sp*128 + hloc);
        float4 bf4 = *(const float4*)(fb12 + 1024 + sp*128 + hloc);
        __syncthreads();   // previous sub-pass GEMM2 done reading sH
        #pragma unroll
        for (int m=0;m<8;++m) {
            const int tok = m*16 + l16;
            float g0 = ag[m][0]+bg4.x, g1 = ag[m][1]+bg4.y;
            float g2 = ag[m][2]+bg4.z, g3 = ag[m][3]+bg4.w;
            float h0 = g0*__builtin_amdgcn_rcpf(1.f+__expf(-g0))*(af[m][0]+bf4.x);
            float h1 = g1*__builtin_amdgcn_rcpf(1.f+__expf(-g1))*(af[m][1]+bf4.y);
            float h2 = g2*__builtin_amdgcn_rcpf(1.f+__expf(-g2))*(af[m][2]+bf4.z);
            float h3 = g3*__builtin_amdgcn_rcpf(1.f+__expf(-g3))*(af[m][3]+bf4.w);
            st_bf4(&sH[tok*128 + (hloc ^ ((tok&7)<<3))], h0, h1, h2, h3);
        }
        bf16x8 bb[4][2];
        #pragma unroll
        for (int c=0;c<4;++c)
            #pragma unroll
            for (int n=0;n<2;++n) {
                const int ob = wid*2 + n, kc = sp*4 + c;
                bb[c][n] = *(const bf16x8*)(w2f + ((size_t)(ob*32 + kc)*64 + l)*8);
            }
        __syncthreads();   // sH ready
        #pragma unroll
        for (int c=0;c<4;++c) {
            bf16x8 ah[8];
            #pragma unroll
            for (int m=0;m<8;++m) {
                const int tok = m*16 + l16;
                ah[m] = *(const bf16x8*)&sH[tok*128 + ((c*32 + lg*8) ^ ((tok&7)<<3))];
            }
            #pragma unroll
            for (int n=0;n<2;++n)
                #pragma unroll
                for (int m=0;m<8;++m)
                    acc2[m][n] = mfma16(ah[m], bb[c][n], acc2[m][n]);
        }
    }
    #pragma unroll
    for (int n=0;n<2;++n) {
        const int col = wid*32 + n*16 + l16;
        const float bv = fb2[col];
        #pragma unroll
        for (int m=0;m<8;++m)
            #pragma unroll
            for (int r=0;r<4;++r) {
                const size_t idx = (m0 + m*16 + lg*4 + r)*256 + col;
                out[idx] += acc2[m][n][r] + bv;
            }
    }
}

// ---------------------------------------------------------------------------
extern "C" void kernel_launch(void* const* d_in, const int* in_sizes, int n_in,
                              void* d_out, int out_size, void* d_ws, size_t ws_size,
                              hipStream_t stream) {
    const float* x      = (const float*)d_in[0];
    const float* n1w    = (const float*)d_in[1];
    const float* n1b    = (const float*)d_in[2];
    const float* qkvw   = (const float*)d_in[3];
    const float* qkvb   = (const float*)d_in[4];
    const float* projw  = (const float*)d_in[5];
    const float* projb  = (const float*)d_in[6];
    const float* rpb    = (const float*)d_in[7];
    const float* n2w    = (const float*)d_in[8];
    const float* n2b    = (const float*)d_in[9];
    const float* fc12w  = (const float*)d_in[10];
    const float* fc12b  = (const float*)d_in[11];
    const float* fc2w   = (const float*)d_in[12];
    const float* fc2b   = (const float*)d_in[13];
    float* out = (float*)d_out;

    char* ws = (char*)d_ws;
    bf16* wb       = (bf16*)ws;                        // 2 MiB converted weights
    bf16* qkvw_bf  = wb;
    bf16* projw_bf = wb + 196608;
    bf16* w12f_bf  = wb + 262144;
    bf16* w2f_bf   = wb + 786432;
    float* biasTab = (float*)(ws + 2097152);           // 512 KiB
    bf16* Qb  = (bf16*)(ws + 2621440);                 // 64 MiB
    bf16* Kb  = (bf16*)(ws + 69730304);                // 64 MiB
    bf16* Vt  = (bf16*)(ws + 136839168);               // 64 MiB (V transposed)
    bf16* xn1 = (bf16*)(ws + 203948032);               // 64 MiB (reused as ao)
    bf16* ao  = (bf16*)(ws + 203948032);
    bf16* xn2 = (bf16*)(ws + 2621440);                 // over Qb (dead after attn)

    k_cvtw<<<512, 256, 0, stream>>>(qkvw, projw, fc12w, fc2w, wb);
    k_mkbias<<<512, 256, 0, stream>>>(rpb, biasTab);
    k_ln_win<<<32768, 256, 0, stream>>>(x, n1w, n1b, xn1);
    k_qkv<<<dim3(6, 1024), 256, 0, stream>>>(xn1, qkvw_bf, qkvb, Qb, Kb, Vt);
    k_attn<<<2048, 256, 0, stream>>>(Qb, Kb, Vt, biasTab, ao);
    k_proj<<<1024, 256, 0, stream>>>(ao, projw_bf, projb, x, n2w, n2b, out, xn2);
    k_mlp<<<1024, 512, 0, stream>>>(xn2, w12f_bf, fc12b, w2f_bf, fc2b, out);
}

// Round 12
// 705.153 us; speedup vs baseline: 1.2566x; 1.0064x over previous
//
#include <hip/hip_runtime.h>
#include <hip/hip_bf16.h>
#include <stdint.h>

typedef __bf16 bf16;
typedef __bf16 bf16x4 __attribute__((ext_vector_type(4)));
typedef __bf16 bf16x8 __attribute__((ext_vector_type(8)));
typedef float  f32x4  __attribute__((ext_vector_type(4)));
typedef unsigned int u32;

__device__ __forceinline__ f32x4 mfma16(bf16x8 a, bf16x8 b, f32x4 c) {
    return __builtin_amdgcn_mfma_f32_16x16x32_bf16(a, b, c, 0, 0, 0);
}
__device__ __forceinline__ void st_bf4(bf16* p, float a, float b, float c, float d) {
    bf16x4 v = { (bf16)a, (bf16)b, (bf16)c, (bf16)d };
    *(bf16x4*)p = v;
}
// async global->LDS, 16B per lane; LDS dest = wave-uniform base + lane*16
__device__ __forceinline__ void gl16(const bf16* g, bf16* l) {
    __builtin_amdgcn_global_load_lds(
        (const __attribute__((address_space(1))) u32*)g,
        (__attribute__((address_space(3))) u32*)l, 16, 0, 0);
}

// ---------------------------------------------------------------------------
// weights f32 -> bf16.  qkvw/projw linear; fc12w/fc2w permuted into
// per-wave-fragment order so one wave load = 1 KB contiguous.
// ---------------------------------------------------------------------------
__global__ __launch_bounds__(256) void k_cvtw(
    const float* __restrict__ qkvw, const float* __restrict__ projw,
    const float* __restrict__ f12w, const float* __restrict__ f2w,
    bf16* __restrict__ wb)
{
    const int i = blockIdx.x * 256 + threadIdx.x;   // one 8-elem chunk
    const size_t doff = (size_t)i * 8;
    const float* src; size_t soff;
    if (i < 24576) {            // qkv linear (196608 elems)
        src = qkvw; soff = doff;
    } else if (i < 32768) {     // proj linear (65536)
        src = projw; soff = doff - 196608;
    } else if (i < 98304) {     // w12f permuted (524288)
        const int i3 = i - 32768;
        const int hrow16 = i3 >> 9, ks = (i3 >> 6) & 7, l = i3 & 63;
        src = f12w;
        soff = (size_t)(hrow16*16 + (l&15))*256 + ks*32 + (l>>4)*8;
    } else {                    // w2f permuted (262144)
        const int i4 = i - 98304;
        const int ob = i4 >> 11, kc = (i4 >> 6) & 31, l = i4 & 63;
        src = f2w;
        soff = (size_t)(ob*16 + (l&15))*1024 + kc*32 + (l>>4)*8;
    }
    float4 a = *(const float4*)(src + soff);
    float4 b = *(const float4*)(src + soff + 4);
    bf16x8 v = { (bf16)a.x,(bf16)a.y,(bf16)a.z,(bf16)a.w,
                 (bf16)b.x,(bf16)b.y,(bf16)b.z,(bf16)b.w };
    *(bf16x8*)(wb + doff) = v;
}

// ---------------------------------------------------------------------------
// bias+mask table, SWAPPED-QK fragment layout:
// idx = (((type*8+h)*4 + nt)*4 + wv)*256 + l*4 + r
// m(key) = nt*16 + (l>>4)*4 + r ; n(query) = wv*16 + (l&15)
// One f32x4 load per lane is fully coalesced.
// ---------------------------------------------------------------------------
__global__ __launch_bounds__(256) void k_mkbias(
    const float* __restrict__ rpb, float* __restrict__ tab)
{
    const int idx = blockIdx.x * 256 + threadIdx.x;
    const int r = idx & 3, l = (idx >> 2) & 63;
    const int wv = (idx >> 8) & 3, nt = (idx >> 10) & 3;
    const int h = (idx >> 12) & 7, type = idx >> 15;
    const int m = nt*16 + ((l >> 4) << 2) + r;   // key token
    const int n = wv*16 + (l & 15);              // query token
    const int mr = m >> 3, mc = m & 7, nr = n >> 3, nc = n & 7;
    float bv = rpb[((nr - mr + 7) * 15 + (nc - mc + 7)) * 8 + h];
    const int ter = type >> 1, tec = type & 1;
    const int hm = ter ? ((mr < 4) ? 1 : 2) : 0;
    const int wm = tec ? ((mc < 4) ? 1 : 2) : 0;
    const int hn = ter ? ((nr < 4) ? 1 : 2) : 0;
    const int wn = tec ? ((nc < 4) ? 1 : 2) : 0;
    if (hm != hn || wm != wn) bv -= 100.f;
    tab[idx] = bv;
}

// ---------------------------------------------------------------------------
// LN1 + window gather: output rows in window order (b,win,tok)
// ---------------------------------------------------------------------------
__global__ __launch_bounds__(256) void k_ln_win(
    const float* __restrict__ in, const float* __restrict__ gw_,
    const float* __restrict__ gb_, bf16* __restrict__ o)
{
    const int tid = threadIdx.x;
    const int wv = tid >> 6, ln = tid & 63;
    const size_t drow = (size_t)blockIdx.x * 4 + wv;
    const int b = drow >> 12, win = (drow >> 6) & 63, tok = drow & 63;
    const int wr = win >> 3, wc = win & 7, tr = tok >> 3, tc = tok & 7;
    const int hs = (wr * 8 + tr + 4) & 63, vs = (wc * 8 + tc + 4) & 63;
    const size_t srow = ((size_t)b << 12) | (hs << 6) | vs;
    const float* src = in + srow * 256;
    float4 v = *(const float4*)(src + ln * 4);
    float s = v.x + v.y + v.z + v.w;
    float q = v.x*v.x + v.y*v.y + v.z*v.z + v.w*v.w;
    #pragma unroll
    for (int ofs = 32; ofs; ofs >>= 1) { s += __shfl_xor(s, ofs); q += __shfl_xor(q, ofs); }
    const float mean = s * (1.0f/256.0f);
    const float var  = q * (1.0f/256.0f) - mean * mean;
    const float rstd = rsqrtf(var + 1e-5f);
    float4 gw = *(const float4*)(gw_ + ln*4);
    float4 gb = *(const float4*)(gb_ + ln*4);
    st_bf4(o + drow*256 + ln*4,
           (v.x-mean)*rstd*gw.x + gb.x, (v.y-mean)*rstd*gw.y + gb.y,
           (v.z-mean)*rstd*gw.z + gb.z, (v.w-mean)*rstd*gw.w + gb.w);
}

// ---------------------------------------------------------------------------
// QKV GEMM (window-ordered rows): Q/K linear window-major; V computed with
// SWAPPED mfma so the epilogue writes V^T [win][chan][tok] coalesced.
// Grid (6, 1024): N-blocks sharing an A-tile are dispatch-adjacent (L2 reuse).
// ---------------------------------------------------------------------------
__global__ __launch_bounds__(256) void k_qkv(
    const bf16* __restrict__ A, const bf16* __restrict__ Bw,
    const float* __restrict__ qkvb,
    bf16* __restrict__ Qb, bf16* __restrict__ Kb, bf16* __restrict__ Vt)
{
    __shared__ bf16 sA[128*32];
    __shared__ bf16 sB[128*32];
    const int tid = threadIdx.x, w = tid>>6, l = tid&63;
    const int l16 = l&15, lg = l>>4;
    const int wm = w>>1, wn = w&1;
    const int m0 = blockIdx.y<<7, n0 = blockIdx.x<<7;
    const bool vseg = (n0 >= 512);
    const int srow = l>>2;
    const int gk = ((l&3) ^ ((l>>3)&3)) << 3;
    const bf16* gA0 = A + (size_t)(m0 + w*32 + srow)*256 + gk;
    const bf16* gA1 = gA0 + 16*256;
    const bf16* gB0 = Bw + (size_t)(n0 + w*32 + srow)*256 + gk;
    const bf16* gB1 = gB0 + 16*256;
    bf16* lA0 = &sA[(w*32)*32];
    bf16* lA1 = &sA[(w*32+16)*32];
    bf16* lB0 = &sB[(w*32)*32];
    bf16* lB1 = &sB[(w*32+16)*32];
    const int slot = lg ^ ((l16>>1)&3);
    int adA[4], adB[4];
    #pragma unroll
    for (int i=0;i<4;++i) {
        adA[i] = (wm*64 + i*16 + l16)*32 + slot*8;
        adB[i] = (wn*64 + i*16 + l16)*32 + slot*8;
    }
    f32x4 acc[4][4] = {};
    for (int ks = 0; ks < 8; ++ks) {
        gl16(gA0 + ks*32, lA0); gl16(gA1 + ks*32, lA1);
        gl16(gB0 + ks*32, lB0); gl16(gB1 + ks*32, lB1);
        __syncthreads();
        bf16x8 av[4], bv[4];
        #pragma unroll
        for (int i=0;i<4;++i) { av[i] = *(const bf16x8*)&sA[adA[i]]; bv[i] = *(const bf16x8*)&sB[adB[i]]; }
        if (!vseg) {
            #pragma unroll
            for (int mi=0;mi<4;++mi)
                #pragma unroll
                for (int ni=0;ni<4;++ni)
                    acc[mi][ni] = mfma16(av[mi], bv[ni], acc[mi][ni]);
        } else {
            #pragma unroll
            for (int mi=0;mi<4;++mi)
                #pragma unroll
                for (int ni=0;ni<4;++ni)
                    acc[mi][ni] = mfma16(bv[ni], av[mi], acc[mi][ni]);
        }
        __syncthreads();
    }
    if (!vseg) {
        #pragma unroll
        for (int ni=0;ni<4;++ni) {
            const int cg = n0 + wn*64 + ni*16 + l16;
            const int seg = cg >> 8, cs = cg & 255;
            bf16* dst = (seg==0) ? Qb : Kb;
            const float mul = (seg==0) ? 0.1767766952966369f : 1.0f;
            const float bias = qkvb[cg];
            #pragma unroll
            for (int mi=0;mi<4;++mi) {
                const int row = m0 + wm*64 + mi*16 + lg*4;
                #pragma unroll
                for (int r=0;r<4;++r)
                    dst[(size_t)(row+r)*256 + cs] = (bf16)((acc[mi][ni][r] + bias)*mul);
            }
        }
    } else {
        const int winb = (m0 >> 6) + wm;
        #pragma unroll
        for (int ni=0;ni<4;++ni) {
            const int ch0 = (n0 - 512) + wn*64 + ni*16 + lg*4;
            const float4 b4 = *(const float4*)(qkvb + 512 + ch0);
            const float barr[4] = { b4.x, b4.y, b4.z, b4.w };
            #pragma unroll
            for (int mi=0;mi<4;++mi) {
                const int tok = mi*16 + l16;
                #pragma unroll
                for (int r=0;r<4;++r)
                    Vt[(size_t)winb*16384 + (size_t)(ch0+r)*64 + tok] =
                        (bf16)(acc[mi][ni][r] + barr[r]);
            }
        }
    }
}

// ---------------------------------------------------------------------------
// window attention v5: swapped QK^T (S^T in regs -> in-lane softmax over k:
// 16 in-lane values + 2 shuffles), coalesced bias loads, b64 sP stores,
// 2-head buffered coalesced output flush. No barriers, K/V from L2.
// ---------------------------------------------------------------------------
__global__ __launch_bounds__(256) void k_attn(
    const bf16* __restrict__ Qb, const bf16* __restrict__ Kb,
    const bf16* __restrict__ Vt, const float* __restrict__ biasTab,
    bf16* __restrict__ ao)
{
    __shared__ bf16 sP[64][72];
    __shared__ bf16 sO2[64][68];
    const int tid = threadIdx.x;
    const int wv = tid>>6, l = tid&63, l16 = l&15, lg = l>>4;
    const int win = blockIdx.x, ww = win&63;
    const int type = (((ww>>3)==7)?2:0) | (((ww&7)==7)?1:0);

    const bf16* Kw = Kb + (size_t)win*16384;
    const bf16* Vw = Vt + (size_t)win*16384;

    // Q fragments, all 8 heads
    const size_t qoff = ((size_t)win*64 + wv*16 + l16)*256 + lg*8;
    bf16x8 qf[8];
    #pragma unroll
    for (int h=0;h<8;++h) qf[h] = *(const bf16x8*)(Qb + qoff + h*32);

    // K fragments for head 0 (prefetched one head ahead thereafter)
    bf16x8 kb[4];
    #pragma unroll
    for (int nt=0;nt<4;++nt)
        kb[nt] = *(const bf16x8*)(Kw + (size_t)(nt*16+l16)*256 + lg*8);

    const float* tb0 = biasTab + ((size_t)type<<15);

    for (int h=0; h<8; ++h) {
        const float* tb = tb0 + (h<<12) + (wv<<8) + l*4;
        // ---- swapped QK^T: at[nt] = S^T[k=nt*16+lg*4+r][q=wv*16+l16] ----
        f32x4 at[4];
        #pragma unroll
        for (int nt=0;nt<4;++nt) {
            f32x4 bias4 = *(const f32x4*)(tb + (nt<<10));
            at[nt] = mfma16(kb[nt], qf[h], bias4);
        }
        if (h < 7) {   // prefetch next head's K under the softmax
            #pragma unroll
            for (int nt=0;nt<4;++nt)
                kb[nt] = *(const bf16x8*)(Kw + (size_t)(nt*16+l16)*256 + (h+1)*32 + lg*8);
        }
        // ---- softmax over k: 16 in-lane + lanes +-16/32 ----
        float mx = at[0][0];
        #pragma unroll
        for (int nt=0;nt<4;++nt)
            #pragma unroll
            for (int r=0;r<4;++r) mx = fmaxf(mx, at[nt][r]);
        mx = fmaxf(mx, __shfl_xor(mx, 16));
        mx = fmaxf(mx, __shfl_xor(mx, 32));
        float p[4][4]; float sm = 0.f;
        #pragma unroll
        for (int nt=0;nt<4;++nt)
            #pragma unroll
            for (int r=0;r<4;++r) { p[nt][r] = __expf(at[nt][r]-mx); sm += p[nt][r]; }
        sm += __shfl_xor(sm, 16);
        sm += __shfl_xor(sm, 32);
        const float inv = __builtin_amdgcn_rcpf(sm);
        #pragma unroll
        for (int nt=0;nt<4;++nt)
            st_bf4(&sP[wv*16+l16][nt*16+lg*4],
                   p[nt][0]*inv, p[nt][1]*inv, p[nt][2]*inv, p[nt][3]*inv);
        // ---- PV ----
        #pragma unroll
        for (int nt=0;nt<2;++nt) {
            f32x4 o = {};
            #pragma unroll
            for (int ks=0;ks<2;++ks) {
                bf16x8 pa = *(const bf16x8*)&sP[wv*16+l16][ks*32+lg*8];
                bf16x8 vb = *(const bf16x8*)(Vw + (size_t)(h*32+nt*16+l16)*64 + ks*32 + lg*8);
                o = mfma16(pa, vb, o);
            }
            #pragma unroll
            for (int r=0;r<4;++r)
                sO2[wv*16 + lg*4 + r][(h&1)*32 + nt*16 + l16] = (bf16)o[r];
        }
        if (h & 1) {   // flush heads h-1,h: coalesced 8B stores (same-wave rows)
            #pragma unroll
            for (int r=0;r<4;++r) {
                const int row = wv*16 + lg*4 + r;
                *(uint2*)(ao + ((size_t)win*64 + row)*256 + (h-1)*32 + l16*4) =
                    *(const uint2*)&sO2[row][l16*4];
            }
        }
    }
}

// ---------------------------------------------------------------------------
// proj GEMM (128x256, K=256) + reverse-shift scatter + residual + LN2 fused
// ---------------------------------------------------------------------------
__global__ __launch_bounds__(256) void k_proj(
    const bf16* __restrict__ ao, const bf16* __restrict__ Bw,
    const float* __restrict__ projb, const float* __restrict__ x,
    const float* __restrict__ n2w, const float* __restrict__ n2b,
    float* __restrict__ out, bf16* __restrict__ xn2)
{
    __shared__ bf16 sA[128*32];
    __shared__ bf16 sB[256*32];
    const int tid = threadIdx.x, w = tid>>6, l = tid&63;
    const int l16 = l&15, lg = l>>4;
    const int m0 = blockIdx.x<<7;
    const int srow = l>>2;
    const int gk = ((l&3) ^ ((l>>3)&3)) << 3;
    const bf16* gA0 = ao + (size_t)(m0 + w*32 + srow)*256 + gk;
    const bf16* gA1 = gA0 + 16*256;
    const bf16* gB0 = Bw + (size_t)(w*64 + srow)*256 + gk;
    bf16* lA0 = &sA[(w*32)*32];
    bf16* lA1 = &sA[(w*32+16)*32];
    bf16* lB0 = &sB[(w*64)*32];
    const int slot = lg ^ ((l16>>1)&3);
    const int adA0 = (w*32 + l16)*32 + slot*8;
    const int adA1 = (w*32+16 + l16)*32 + slot*8;
    f32x4 acc[2][16] = {};
    for (int ks=0; ks<8; ++ks) {
        gl16(gA0 + ks*32, lA0); gl16(gA1 + ks*32, lA1);
        #pragma unroll
        for (int i=0;i<4;++i)
            gl16(gB0 + i*16*256 + ks*32, lB0 + i*16*32);
        __syncthreads();
        bf16x8 a0 = *(const bf16x8*)&sA[adA0];
        bf16x8 a1 = *(const bf16x8*)&sA[adA1];
        #pragma unroll
        for (int nj=0;nj<16;++nj) {
            bf16x8 bvv = *(const bf16x8*)&sB[(nj*16 + l16)*32 + slot*8];
            acc[0][nj] = mfma16(a0, bvv, acc[0][nj]);
            acc[1][nj] = mfma16(a1, bvv, acc[1][nj]);
        }
        __syncthreads();
    }
    #pragma unroll
    for (int mi=0;mi<2;++mi) {
        #pragma unroll
        for (int rr=0;rr<4;++rr) {
            const int rgw = m0 + w*32 + mi*16 + lg*4 + rr;
            const int win = rgw>>6, tok = rgw&63;
            const int bb = win>>6, wwi = win&63;
            const int wr = wwi>>3, wc = wwi&7, tr = tok>>3, tc = tok&7;
            const int hs = (wr*8+tr+4)&63, vs = (wc*8+tc+4)&63;
            const size_t grow = ((size_t)bb<<12) + (hs<<6) + vs;
            float vals[16]; float s=0.f, s2=0.f;
            #pragma unroll
            for (int nj=0;nj<16;++nj) {
                const int col = nj*16 + l16;
                const float t = acc[mi][nj][rr] + projb[col] + x[grow*256 + col];
                vals[nj] = t; s += t; s2 += t*t;
            }
            #pragma unroll
            for (int ofs=8;ofs;ofs>>=1){ s += __shfl_xor(s,ofs); s2 += __shfl_xor(s2,ofs); }
            const float mean = s*(1.f/256.f);
            const float rstd = rsqrtf(s2*(1.f/256.f) - mean*mean + 1e-5f);
            #pragma unroll
            for (int nj=0;nj<16;++nj) {
                const int col = nj*16 + l16;
                out[grow*256+col] = vals[nj];
                xn2[grow*256+col] = (bf16)((vals[nj]-mean)*rstd*n2w[col] + n2b[col]);
            }
        }
    }
}

// ---------------------------------------------------------------------------
// fused MLP v4 (r7-measured 255 us) + full-granule sH swizzle ((tok&15)<<3):
// 16 distinct 8B-granule positions per 16-lane group on stores AND reads.
// M=128 tokens, 512 threads (8 waves), 8 sub-passes of 128 hidden.
// LDS = 64 KB sA + 32 KB sH = 96 KB -> 1 block/CU.
// ---------------------------------------------------------------------------
__global__ __launch_bounds__(512, 2) void k_mlp(
    const bf16* __restrict__ xn2, const bf16* __restrict__ w12f,
    const float* __restrict__ fb12, const bf16* __restrict__ w2f,
    const float* __restrict__ fb2, float* __restrict__ out)
{
    __shared__ bf16 sA[8*128*32];   // 64 KB: [ks][128 tok][32] swizzled acts
    __shared__ bf16 sH[128*128];    // 32 KB: [tok][128 hid] XOR-swizzled
    const int tid = threadIdx.x, wid = tid>>6, l = tid&63;
    const int l16 = l&15, lg = l>>4;
    const size_t m0 = (size_t)blockIdx.x << 7;
    const int srow = l>>2;
    const int gk = ((l&3) ^ ((l>>3)&3)) << 3;
    const bf16* gA = xn2 + (m0 + wid*16 + srow)*256 + gk;
    #pragma unroll
    for (int ks=0; ks<8; ++ks)
        gl16(gA + ks*32, &sA[(ks*128 + wid*16)*32]);

    const int slot = lg ^ ((l16>>1)&3);
    f32x4 acc2[8][2] = {};
    __syncthreads();

    for (int sp = 0; sp < 8; ++sp) {
        const bf16* pg = w12f + ((size_t)(sp*8 + wid) * 8) * 512;       // gate
        const bf16* pf = w12f + ((size_t)(sp*8 + wid + 64) * 8) * 512;  // feat
        f32x4 ag[8] = {}, af[8] = {};
        #pragma unroll
        for (int ks=0; ks<8; ++ks) {
            bf16x8 wg = *(const bf16x8*)(pg + ks*512 + l*8);
            bf16x8 wf = *(const bf16x8*)(pf + ks*512 + l*8);
            #pragma unroll
            for (int m=0;m<8;++m) {
                bf16x8 av = *(const bf16x8*)&sA[(ks*128 + m*16 + l16)*32 + slot*8];
                ag[m] = mfma16(wg, av, ag[m]);
                af[m] = mfma16(wf, av, af[m]);
            }
        }
        const int hloc = wid*16 + lg*4;
        float4 bg4 = *(const float4*)(fb12 + sp*128 + hloc);
        float4 bf4 = *(const float4*)(fb12 + 1024 + sp*128 + hloc);
        __syncthreads();   // previous sub-pass GEMM2 done reading sH
        #pragma unroll
        for (int m=0;m<8;++m) {
            const int tok = m*16 + l16;
            float g0 = ag[m][0]+bg4.x, g1 = ag[m][1]+bg4.y;
            float g2 = ag[m][2]+bg4.z, g3 = ag[m][3]+bg4.w;
            float h0 = g0*__builtin_amdgcn_rcpf(1.f+__expf(-g0))*(af[m][0]+bf4.x);
            float h1 = g1*__builtin_amdgcn_rcpf(1.f+__expf(-g1))*(af[m][1]+bf4.y);
            float h2 = g2*__builtin_amdgcn_rcpf(1.f+__expf(-g2))*(af[m][2]+bf4.z);
            float h3 = g3*__builtin_amdgcn_rcpf(1.f+__expf(-g3))*(af[m][3]+bf4.w);
            st_bf4(&sH[tok*128 + (hloc ^ ((tok&15)<<3))], h0, h1, h2, h3);
        }
        bf16x8 bb[4][2];
        #pragma unroll
        for (int c=0;c<4;++c)
            #pragma unroll
            for (int n=0;n<2;++n) {
                const int ob = wid*2 + n, kc = sp*4 + c;
                bb[c][n] = *(const bf16x8*)(w2f + ((size_t)(ob*32 + kc)*64 + l)*8);
            }
        __syncthreads();   // sH ready
        #pragma unroll
        for (int c=0;c<4;++c) {
            bf16x8 ah[8];
            #pragma unroll
            for (int m=0;m<8;++m) {
                const int tok = m*16 + l16;
                ah[m] = *(const bf16x8*)&sH[tok*128 + ((c*32 + lg*8) ^ ((tok&15)<<3))];
            }
            #pragma unroll
            for (int n=0;n<2;++n)
                #pragma unroll
                for (int m=0;m<8;++m)
                    acc2[m][n] = mfma16(ah[m], bb[c][n], acc2[m][n]);
        }
    }
    #pragma unroll
    for (int n=0;n<2;++n) {
        const int col = wid*32 + n*16 + l16;
        const float bv = fb2[col];
        #pragma unroll
        for (int m=0;m<8;++m)
            #pragma unroll
            for (int r=0;r<4;++r) {
                const size_t idx = (m0 + m*16 + lg*4 + r)*256 + col;
                out[idx] += acc2[m][n][r] + bv;
            }
    }
}

// ---------------------------------------------------------------------------
extern "C" void kernel_launch(void* const* d_in, const int* in_sizes, int n_in,
                              void* d_out, int out_size, void* d_ws, size_t ws_size,
                              hipStream_t stream) {
    const float* x      = (const float*)d_in[0];
    const float* n1w    = (const float*)d_in[1];
    const float* n1b    = (const float*)d_in[2];
    const float* qkvw   = (const float*)d_in[3];
    const float* qkvb   = (const float*)d_in[4];
    const float* projw  = (const float*)d_in[5];
    const float* projb  = (const float*)d_in[6];
    const float* rpb    = (const float*)d_in[7];
    const float* n2w    = (const float*)d_in[8];
    const float* n2b    = (const float*)d_in[9];
    const float* fc12w  = (const float*)d_in[10];
    const float* fc12b  = (const float*)d_in[11];
    const float* fc2w   = (const float*)d_in[12];
    const float* fc2b   = (const float*)d_in[13];
    float* out = (float*)d_out;

    char* ws = (char*)d_ws;
    bf16* wb       = (bf16*)ws;                        // 2 MiB converted weights
    bf16* qkvw_bf  = wb;
    bf16* projw_bf = wb + 196608;
    bf16* w12f_bf  = wb + 262144;
    bf16* w2f_bf   = wb + 786432;
    float* biasTab = (float*)(ws + 2097152);           // 512 KiB
    bf16* Qb  = (bf16*)(ws + 2621440);                 // 64 MiB
    bf16* Kb  = (bf16*)(ws + 69730304);                // 64 MiB
    bf16* Vt  = (bf16*)(ws + 136839168);               // 64 MiB (V transposed)
    bf16* xn1 = (bf16*)(ws + 203948032);               // 64 MiB (reused as ao)
    bf16* ao  = (bf16*)(ws + 203948032);
    bf16* xn2 = (bf16*)(ws + 2621440);                 // over Qb (dead after attn)

    k_cvtw<<<512, 256, 0, stream>>>(qkvw, projw, fc12w, fc2w, wb);
    k_mkbias<<<512, 256, 0, stream>>>(rpb, biasTab);
    k_ln_win<<<32768, 256, 0, stream>>>(x, n1w, n1b, xn1);
    k_qkv<<<dim3(6, 1024), 256, 0, stream>>>(xn1, qkvw_bf, qkvb, Qb, Kb, Vt);
    k_attn<<<2048, 256, 0, stream>>>(Qb, Kb, Vt, biasTab, ao);
    k_proj<<<1024, 256, 0, stream>>>(ao, projw_bf, projb, x, n2w, n2b, out, xn2);
    k_mlp<<<1024, 512, 0, stream>>>(xn2, w12f_bf, fc12b, w2f_bf, fc2b, out);
}

// Round 13
// 577.616 us; speedup vs baseline: 1.5341x; 1.2208x over previous
//
#include <hip/hip_runtime.h>
#include <hip/hip_bf16.h>
#include <stdint.h>

typedef __bf16 bf16;
typedef __bf16 bf16x4 __attribute__((ext_vector_type(4)));
typedef __bf16 bf16x8 __attribute__((ext_vector_type(8)));
typedef float  f32x4  __attribute__((ext_vector_type(4)));
typedef unsigned int u32;

__device__ __forceinline__ f32x4 mfma16(bf16x8 a, bf16x8 b, f32x4 c) {
    return __builtin_amdgcn_mfma_f32_16x16x32_bf16(a, b, c, 0, 0, 0);
}
__device__ __forceinline__ void st_bf4(bf16* p, float a, float b, float c, float d) {
    bf16x4 v = { (bf16)a, (bf16)b, (bf16)c, (bf16)d };
    *(bf16x4*)p = v;
}
// async global->LDS, 16B per lane; LDS dest = wave-uniform base + lane*16
__device__ __forceinline__ void gl16(const bf16* g, bf16* l) {
    __builtin_amdgcn_global_load_lds(
        (const __attribute__((address_space(1))) u32*)g,
        (__attribute__((address_space(3))) u32*)l, 16, 0, 0);
}

// ---------------------------------------------------------------------------
// weights f32 -> bf16.  qkvw/projw linear; fc12w/fc2w permuted into
// per-wave-fragment order so one wave load = 1 KB contiguous.
// ---------------------------------------------------------------------------
__global__ __launch_bounds__(256) void k_cvtw(
    const float* __restrict__ qkvw, const float* __restrict__ projw,
    const float* __restrict__ f12w, const float* __restrict__ f2w,
    bf16* __restrict__ wb)
{
    const int i = blockIdx.x * 256 + threadIdx.x;   // one 8-elem chunk
    const size_t doff = (size_t)i * 8;
    const float* src; size_t soff;
    if (i < 24576) {            // qkv linear (196608 elems)
        src = qkvw; soff = doff;
    } else if (i < 32768) {     // proj linear (65536)
        src = projw; soff = doff - 196608;
    } else if (i < 98304) {     // w12f permuted (524288)
        const int i3 = i - 32768;
        const int hrow16 = i3 >> 9, ks = (i3 >> 6) & 7, l = i3 & 63;
        src = f12w;
        soff = (size_t)(hrow16*16 + (l&15))*256 + ks*32 + (l>>4)*8;
    } else {                    // w2f permuted (262144)
        const int i4 = i - 98304;
        const int ob = i4 >> 11, kc = (i4 >> 6) & 31, l = i4 & 63;
        src = f2w;
        soff = (size_t)(ob*16 + (l&15))*1024 + kc*32 + (l>>4)*8;
    }
    float4 a = *(const float4*)(src + soff);
    float4 b = *(const float4*)(src + soff + 4);
    bf16x8 v = { (bf16)a.x,(bf16)a.y,(bf16)a.z,(bf16)a.w,
                 (bf16)b.x,(bf16)b.y,(bf16)b.z,(bf16)b.w };
    *(bf16x8*)(wb + doff) = v;
}

// ---------------------------------------------------------------------------
// bias+mask table, SWAPPED-QK fragment layout:
// idx = (((type*8+h)*4 + nt)*4 + wv)*256 + l*4 + r
// m(key) = nt*16 + (l>>4)*4 + r ; n(query) = wv*16 + (l&15)
// ---------------------------------------------------------------------------
__global__ __launch_bounds__(256) void k_mkbias(
    const float* __restrict__ rpb, float* __restrict__ tab)
{
    const int idx = blockIdx.x * 256 + threadIdx.x;
    const int r = idx & 3, l = (idx >> 2) & 63;
    const int wv = (idx >> 8) & 3, nt = (idx >> 10) & 3;
    const int h = (idx >> 12) & 7, type = idx >> 15;
    const int m = nt*16 + ((l >> 4) << 2) + r;   // key token
    const int n = wv*16 + (l & 15);              // query token
    const int mr = m >> 3, mc = m & 7, nr = n >> 3, nc = n & 7;
    float bv = rpb[((nr - mr + 7) * 15 + (nc - mc + 7)) * 8 + h];
    const int ter = type >> 1, tec = type & 1;
    const int hm = ter ? ((mr < 4) ? 1 : 2) : 0;
    const int wm = tec ? ((mc < 4) ? 1 : 2) : 0;
    const int hn = ter ? ((nr < 4) ? 1 : 2) : 0;
    const int wn = tec ? ((nc < 4) ? 1 : 2) : 0;
    if (hm != hn || wm != wn) bv -= 100.f;
    tab[idx] = bv;
}

// ---------------------------------------------------------------------------
// LN1 + window gather: output rows in window order (b,win,tok)
// ---------------------------------------------------------------------------
__global__ __launch_bounds__(256) void k_ln_win(
    const float* __restrict__ in, const float* __restrict__ gw_,
    const float* __restrict__ gb_, bf16* __restrict__ o)
{
    const int tid = threadIdx.x;
    const int wv = tid >> 6, ln = tid & 63;
    const size_t drow = (size_t)blockIdx.x * 4 + wv;
    const int b = drow >> 12, win = (drow >> 6) & 63, tok = drow & 63;
    const int wr = win >> 3, wc = win & 7, tr = tok >> 3, tc = tok & 7;
    const int hs = (wr * 8 + tr + 4) & 63, vs = (wc * 8 + tc + 4) & 63;
    const size_t srow = ((size_t)b << 12) | (hs << 6) | vs;
    const float* src = in + srow * 256;
    float4 v = *(const float4*)(src + ln * 4);
    float s = v.x + v.y + v.z + v.w;
    float q = v.x*v.x + v.y*v.y + v.z*v.z + v.w*v.w;
    #pragma unroll
    for (int ofs = 32; ofs; ofs >>= 1) { s += __shfl_xor(s, ofs); q += __shfl_xor(q, ofs); }
    const float mean = s * (1.0f/256.0f);
    const float var  = q * (1.0f/256.0f) - mean * mean;
    const float rstd = rsqrtf(var + 1e-5f);
    float4 gw = *(const float4*)(gw_ + ln*4);
    float4 gb = *(const float4*)(gb_ + ln*4);
    st_bf4(o + drow*256 + ln*4,
           (v.x-mean)*rstd*gw.x + gb.x, (v.y-mean)*rstd*gw.y + gb.y,
           (v.z-mean)*rstd*gw.z + gb.z, (v.w-mean)*rstd*gw.w + gb.w);
}

// ---------------------------------------------------------------------------
// QKV GEMM (window-ordered rows): Q/K linear window-major; V computed with
// SWAPPED mfma so the epilogue writes V^T [win][chan][tok] coalesced.
// Grid (6, 1024): N-blocks sharing an A-tile are dispatch-adjacent (L2 reuse).
// ---------------------------------------------------------------------------
__global__ __launch_bounds__(256) void k_qkv(
    const bf16* __restrict__ A, const bf16* __restrict__ Bw,
    const float* __restrict__ qkvb,
    bf16* __restrict__ Qb, bf16* __restrict__ Kb, bf16* __restrict__ Vt)
{
    __shared__ bf16 sA[128*32];
    __shared__ bf16 sB[128*32];
    const int tid = threadIdx.x, w = tid>>6, l = tid&63;
    const int l16 = l&15, lg = l>>4;
    const int wm = w>>1, wn = w&1;
    const int m0 = blockIdx.y<<7, n0 = blockIdx.x<<7;
    const bool vseg = (n0 >= 512);
    const int srow = l>>2;
    const int gk = ((l&3) ^ ((l>>3)&3)) << 3;
    const bf16* gA0 = A + (size_t)(m0 + w*32 + srow)*256 + gk;
    const bf16* gA1 = gA0 + 16*256;
    const bf16* gB0 = Bw + (size_t)(n0 + w*32 + srow)*256 + gk;
    const bf16* gB1 = gB0 + 16*256;
    bf16* lA0 = &sA[(w*32)*32];
    bf16* lA1 = &sA[(w*32+16)*32];
    bf16* lB0 = &sB[(w*32)*32];
    bf16* lB1 = &sB[(w*32+16)*32];
    const int slot = lg ^ ((l16>>1)&3);
    int adA[4], adB[4];
    #pragma unroll
    for (int i=0;i<4;++i) {
        adA[i] = (wm*64 + i*16 + l16)*32 + slot*8;
        adB[i] = (wn*64 + i*16 + l16)*32 + slot*8;
    }
    f32x4 acc[4][4] = {};
    for (int ks = 0; ks < 8; ++ks) {
        gl16(gA0 + ks*32, lA0); gl16(gA1 + ks*32, lA1);
        gl16(gB0 + ks*32, lB0); gl16(gB1 + ks*32, lB1);
        __syncthreads();
        bf16x8 av[4], bv[4];
        #pragma unroll
        for (int i=0;i<4;++i) { av[i] = *(const bf16x8*)&sA[adA[i]]; bv[i] = *(const bf16x8*)&sB[adB[i]]; }
        if (!vseg) {
            #pragma unroll
            for (int mi=0;mi<4;++mi)
                #pragma unroll
                for (int ni=0;ni<4;++ni)
                    acc[mi][ni] = mfma16(av[mi], bv[ni], acc[mi][ni]);
        } else {
            #pragma unroll
            for (int mi=0;mi<4;++mi)
                #pragma unroll
                for (int ni=0;ni<4;++ni)
                    acc[mi][ni] = mfma16(bv[ni], av[mi], acc[mi][ni]);
        }
        __syncthreads();
    }
    if (!vseg) {
        #pragma unroll
        for (int ni=0;ni<4;++ni) {
            const int cg = n0 + wn*64 + ni*16 + l16;
            const int seg = cg >> 8, cs = cg & 255;
            bf16* dst = (seg==0) ? Qb : Kb;
            const float mul = (seg==0) ? 0.1767766952966369f : 1.0f;
            const float bias = qkvb[cg];
            #pragma unroll
            for (int mi=0;mi<4;++mi) {
                const int row = m0 + wm*64 + mi*16 + lg*4;
                #pragma unroll
                for (int r=0;r<4;++r)
                    dst[(size_t)(row+r)*256 + cs] = (bf16)((acc[mi][ni][r] + bias)*mul);
            }
        }
    } else {
        const int winb = (m0 >> 6) + wm;
        #pragma unroll
        for (int ni=0;ni<4;++ni) {
            const int ch0 = (n0 - 512) + wn*64 + ni*16 + lg*4;
            const float4 b4 = *(const float4*)(qkvb + 512 + ch0);
            const float barr[4] = { b4.x, b4.y, b4.z, b4.w };
            #pragma unroll
            for (int mi=0;mi<4;++mi) {
                const int tok = mi*16 + l16;
                #pragma unroll
                for (int r=0;r<4;++r)
                    Vt[(size_t)winb*16384 + (size_t)(ch0+r)*64 + tok] =
                        (bf16)(acc[mi][ni][r] + barr[r]);
            }
        }
    }
}

// ---------------------------------------------------------------------------
// window attention v6: swapped QK^T + in-lane softmax + FULL prefetch chain:
// Q/K/bias double-buffered (h+1 issues under h's softmax); V frags issue
// right after the QK MFMAs so they land under the softmax VALU chain.
// No barriers; only sP (9 KB) + sO2 (8.7 KB) in LDS.
// ---------------------------------------------------------------------------
__global__ __launch_bounds__(256) void k_attn(
    const bf16* __restrict__ Qb, const bf16* __restrict__ Kb,
    const bf16* __restrict__ Vt, const float* __restrict__ biasTab,
    bf16* __restrict__ ao)
{
    __shared__ bf16 sP[64][72];
    __shared__ bf16 sO2[64][68];
    const int tid = threadIdx.x;
    const int wv = tid>>6, l = tid&63, l16 = l&15, lg = l>>4;
    const int win = blockIdx.x, ww = win&63;
    const int type = (((ww>>3)==7)?2:0) | (((ww&7)==7)?1:0);

    const bf16* Kw = Kb + (size_t)win*16384;
    const bf16* Vw = Vt + (size_t)win*16384;
    const bf16* Qw = Qb + ((size_t)win*64 + wv*16 + l16)*256 + lg*8;
    const float* tb0 = biasTab + ((size_t)type<<15) + (wv<<8) + l*4;

    // head-0 preloads: Q frag, K frags, bias frags
    bf16x8 qc = *(const bf16x8*)(Qw);
    bf16x8 qn;
    bf16x8 kb[4];
    f32x4  bc[4];
    #pragma unroll
    for (int nt=0;nt<4;++nt) {
        kb[nt] = *(const bf16x8*)(Kw + (size_t)(nt*16+l16)*256 + lg*8);
        bc[nt] = *(const f32x4*)(tb0 + (nt<<10));
    }

    for (int h=0; h<8; ++h) {
        // ---- swapped QK^T: at[nt] = S^T[k=nt*16+lg*4+r][q=wv*16+l16] ----
        f32x4 at[4];
        #pragma unroll
        for (int nt=0;nt<4;++nt) at[nt] = mfma16(kb[nt], qc, at[nt] = bc[nt]);
        // ---- early-issue this head's V frags (consumed after softmax) ----
        bf16x8 vb[2][2];
        #pragma unroll
        for (int nt=0;nt<2;++nt)
            #pragma unroll
            for (int ks=0;ks<2;++ks)
                vb[nt][ks] = *(const bf16x8*)(Vw + (size_t)(h*32+nt*16+l16)*64 + ks*32 + lg*8);
        // ---- prefetch next head's Q/K/bias (land under softmax) ----
        if (h < 7) {
            qn = *(const bf16x8*)(Qw + (h+1)*32);
            #pragma unroll
            for (int nt=0;nt<4;++nt) {
                kb[nt] = *(const bf16x8*)(Kw + (size_t)(nt*16+l16)*256 + (h+1)*32 + lg*8);
                bc[nt] = *(const f32x4*)(tb0 + ((h+1)<<12) + (nt<<10));
            }
        }
        // ---- softmax over k: 16 in-lane values + lanes ^16/^32 ----
        float mx = at[0][0];
        #pragma unroll
        for (int nt=0;nt<4;++nt)
            #pragma unroll
            for (int r=0;r<4;++r) mx = fmaxf(mx, at[nt][r]);
        mx = fmaxf(mx, __shfl_xor(mx, 16));
        mx = fmaxf(mx, __shfl_xor(mx, 32));
        float p[4][4]; float sm = 0.f;
        #pragma unroll
        for (int nt=0;nt<4;++nt)
            #pragma unroll
            for (int r=0;r<4;++r) { p[nt][r] = __expf(at[nt][r]-mx); sm += p[nt][r]; }
        sm += __shfl_xor(sm, 16);
        sm += __shfl_xor(sm, 32);
        const float inv = __builtin_amdgcn_rcpf(sm);
        #pragma unroll
        for (int nt=0;nt<4;++nt)
            st_bf4(&sP[wv*16+l16][nt*16+lg*4],
                   p[nt][0]*inv, p[nt][1]*inv, p[nt][2]*inv, p[nt][3]*inv);
        // ---- PV (V frags already in regs) ----
        #pragma unroll
        for (int nt=0;nt<2;++nt) {
            f32x4 o = {};
            #pragma unroll
            for (int ks=0;ks<2;++ks) {
                bf16x8 pa = *(const bf16x8*)&sP[wv*16+l16][ks*32+lg*8];
                o = mfma16(pa, vb[nt][ks], o);
            }
            #pragma unroll
            for (int r=0;r<4;++r)
                sO2[wv*16 + lg*4 + r][(h&1)*32 + nt*16 + l16] = (bf16)o[r];
        }
        if (h & 1) {   // flush heads h-1,h: coalesced 8B stores (same-wave rows)
            #pragma unroll
            for (int r=0;r<4;++r) {
                const int row = wv*16 + lg*4 + r;
                *(uint2*)(ao + ((size_t)win*64 + row)*256 + (h-1)*32 + l16*4) =
                    *(const uint2*)&sO2[row][l16*4];
            }
        }
        qc = qn;
    }
}

// ---------------------------------------------------------------------------
// proj GEMM (128x256, K=256) + reverse-shift scatter + residual + LN2 fused
// ---------------------------------------------------------------------------
__global__ __launch_bounds__(256) void k_proj(
    const bf16* __restrict__ ao, const bf16* __restrict__ Bw,
    const float* __restrict__ projb, const float* __restrict__ x,
    const float* __restrict__ n2w, const float* __restrict__ n2b,
    float* __restrict__ out, bf16* __restrict__ xn2)
{
    __shared__ bf16 sA[128*32];
    __shared__ bf16 sB[256*32];
    const int tid = threadIdx.x, w = tid>>6, l = tid&63;
    const int l16 = l&15, lg = l>>4;
    const int m0 = blockIdx.x<<7;
    const int srow = l>>2;
    const int gk = ((l&3) ^ ((l>>3)&3)) << 3;
    const bf16* gA0 = ao + (size_t)(m0 + w*32 + srow)*256 + gk;
    const bf16* gA1 = gA0 + 16*256;
    const bf16* gB0 = Bw + (size_t)(w*64 + srow)*256 + gk;
    bf16* lA0 = &sA[(w*32)*32];
    bf16* lA1 = &sA[(w*32+16)*32];
    bf16* lB0 = &sB[(w*64)*32];
    const int slot = lg ^ ((l16>>1)&3);
    const int adA0 = (w*32 + l16)*32 + slot*8;
    const int adA1 = (w*32+16 + l16)*32 + slot*8;
    f32x4 acc[2][16] = {};
    for (int ks=0; ks<8; ++ks) {
        gl16(gA0 + ks*32, lA0); gl16(gA1 + ks*32, lA1);
        #pragma unroll
        for (int i=0;i<4;++i)
            gl16(gB0 + i*16*256 + ks*32, lB0 + i*16*32);
        __syncthreads();
        bf16x8 a0 = *(const bf16x8*)&sA[adA0];
        bf16x8 a1 = *(const bf16x8*)&sA[adA1];
        #pragma unroll
        for (int nj=0;nj<16;++nj) {
            bf16x8 bvv = *(const bf16x8*)&sB[(nj*16 + l16)*32 + slot*8];
            acc[0][nj] = mfma16(a0, bvv, acc[0][nj]);
            acc[1][nj] = mfma16(a1, bvv, acc[1][nj]);
        }
        __syncthreads();
    }
    #pragma unroll
    for (int mi=0;mi<2;++mi) {
        #pragma unroll
        for (int rr=0;rr<4;++rr) {
            const int rgw = m0 + w*32 + mi*16 + lg*4 + rr;
            const int win = rgw>>6, tok = rgw&63;
            const int bb = win>>6, wwi = win&63;
            const int wr = wwi>>3, wc = wwi&7, tr = tok>>3, tc = tok&7;
            const int hs = (wr*8+tr+4)&63, vs = (wc*8+tc+4)&63;
            const size_t grow = ((size_t)bb<<12) + (hs<<6) + vs;
            float vals[16]; float s=0.f, s2=0.f;
            #pragma unroll
            for (int nj=0;nj<16;++nj) {
                const int col = nj*16 + l16;
                const float t = acc[mi][nj][rr] + projb[col] + x[grow*256 + col];
                vals[nj] = t; s += t; s2 += t*t;
            }
            #pragma unroll
            for (int ofs=8;ofs;ofs>>=1){ s += __shfl_xor(s,ofs); s2 += __shfl_xor(s2,ofs); }
            const float mean = s*(1.f/256.f);
            const float rstd = rsqrtf(s2*(1.f/256.f) - mean*mean + 1e-5f);
            #pragma unroll
            for (int nj=0;nj<16;++nj) {
                const int col = nj*16 + l16;
                out[grow*256+col] = vals[nj];
                xn2[grow*256+col] = (bf16)((vals[nj]-mean)*rstd*n2w[col] + n2b[col]);
            }
        }
    }
}

// ---------------------------------------------------------------------------
// fused MLP v4 (measured-best 254 us): M=128 tokens, 512 threads (8 waves),
// 8 sub-passes of 128 hidden; dup-free 1 KB coalesced weight loads;
// full-granule sH swizzle. LDS = 96 KB -> 1 block/CU.
// ---------------------------------------------------------------------------
__global__ __launch_bounds__(512, 2) void k_mlp(
    const bf16* __restrict__ xn2, const bf16* __restrict__ w12f,
    const float* __restrict__ fb12, const bf16* __restrict__ w2f,
    const float* __restrict__ fb2, float* __restrict__ out)
{
    __shared__ bf16 sA[8*128*32];   // 64 KB: [ks][128 tok][32] swizzled acts
    __shared__ bf16 sH[128*128];    // 32 KB: [tok][128 hid] XOR-swizzled
    const int tid = threadIdx.x, wid = tid>>6, l = tid&63;
    const int l16 = l&15, lg = l>>4;
    const size_t m0 = (size_t)blockIdx.x << 7;
    const int srow = l>>2;
    const int gk = ((l&3) ^ ((l>>3)&3)) << 3;
    const bf16* gA = xn2 + (m0 + wid*16 + srow)*256 + gk;
    #pragma unroll
    for (int ks=0; ks<8; ++ks)
        gl16(gA + ks*32, &sA[(ks*128 + wid*16)*32]);

    const int slot = lg ^ ((l16>>1)&3);
    f32x4 acc2[8][2] = {};
    __syncthreads();

    for (int sp = 0; sp < 8; ++sp) {
        const bf16* pg = w12f + ((size_t)(sp*8 + wid) * 8) * 512;       // gate
        const bf16* pf = w12f + ((size_t)(sp*8 + wid + 64) * 8) * 512;  // feat
        f32x4 ag[8] = {}, af[8] = {};
        #pragma unroll
        for (int ks=0; ks<8; ++ks) {
            bf16x8 wg = *(const bf16x8*)(pg + ks*512 + l*8);
            bf16x8 wf = *(const bf16x8*)(pf + ks*512 + l*8);
            #pragma unroll
            for (int m=0;m<8;++m) {
                bf16x8 av = *(const bf16x8*)&sA[(ks*128 + m*16 + l16)*32 + slot*8];
                ag[m] = mfma16(wg, av, ag[m]);
                af[m] = mfma16(wf, av, af[m]);
            }
        }
        const int hloc = wid*16 + lg*4;
        float4 bg4 = *(const float4*)(fb12 + sp*128 + hloc);
        float4 bf4 = *(const float4*)(fb12 + 1024 + sp*128 + hloc);
        __syncthreads();   // previous sub-pass GEMM2 done reading sH
        #pragma unroll
        for (int m=0;m<8;++m) {
            const int tok = m*16 + l16;
            float g0 = ag[m][0]+bg4.x, g1 = ag[m][1]+bg4.y;
            float g2 = ag[m][2]+bg4.z, g3 = ag[m][3]+bg4.w;
            float h0 = g0*__builtin_amdgcn_rcpf(1.f+__expf(-g0))*(af[m][0]+bf4.x);
            float h1 = g1*__builtin_amdgcn_rcpf(1.f+__expf(-g1))*(af[m][1]+bf4.y);
            float h2 = g2*__builtin_amdgcn_rcpf(1.f+__expf(-g2))*(af[m][2]+bf4.z);
            float h3 = g3*__builtin_amdgcn_rcpf(1.f+__expf(-g3))*(af[m][3]+bf4.w);
            st_bf4(&sH[tok*128 + (hloc ^ ((tok&15)<<3))], h0, h1, h2, h3);
        }
        bf16x8 bb[4][2];
        #pragma unroll
        for (int c=0;c<4;++c)
            #pragma unroll
            for (int n=0;n<2;++n) {
                const int ob = wid*2 + n, kc = sp*4 + c;
                bb[c][n] = *(const bf16x8*)(w2f + ((size_t)(ob*32 + kc)*64 + l)*8);
            }
        __syncthreads();   // sH ready
        #pragma unroll
        for (int c=0;c<4;++c) {
            bf16x8 ah[8];
            #pragma unroll
            for (int m=0;m<8;++m) {
                const int tok = m*16 + l16;
                ah[m] = *(const bf16x8*)&sH[tok*128 + ((c*32 + lg*8) ^ ((tok&15)<<3))];
            }
            #pragma unroll
            for (int n=0;n<2;++n)
                #pragma unroll
                for (int m=0;m<8;++m)
                    acc2[m][n] = mfma16(ah[m], bb[c][n], acc2[m][n]);
        }
    }
    #pragma unroll
    for (int n=0;n<2;++n) {
        const int col = wid*32 + n*16 + l16;
        const float bv = fb2[col];
        #pragma unroll
        for (int m=0;m<8;++m)
            #pragma unroll
            for (int r=0;r<4;++r) {
                const size_t idx = (m0 + m*16 + lg*4 + r)*256 + col;
                out[idx] += acc2[m][n][r] + bv;
            }
    }
}

// ---------------------------------------------------------------------------
extern "C" void kernel_launch(void* const* d_in, const int* in_sizes, int n_in,
                              void* d_out, int out_size, void* d_ws, size_t ws_size,
                              hipStream_t stream) {
    const float* x      = (const float*)d_in[0];
    const float* n1w    = (const float*)d_in[1];
    const float* n1b    = (const float*)d_in[2];
    const float* qkvw   = (const float*)d_in[3];
    const float* qkvb   = (const float*)d_in[4];
    const float* projw  = (const float*)d_in[5];
    const float* projb  = (const float*)d_in[6];
    const float* rpb    = (const float*)d_in[7];
    const float* n2w    = (const float*)d_in[8];
    const float* n2b    = (const float*)d_in[9];
    const float* fc12w  = (const float*)d_in[10];
    const float* fc12b  = (const float*)d_in[11];
    const float* fc2w   = (const float*)d_in[12];
    const float* fc2b   = (const float*)d_in[13];
    float* out = (float*)d_out;

    char* ws = (char*)d_ws;
    bf16* wb       = (bf16*)ws;                        // 2 MiB converted weights
    bf16* qkvw_bf  = wb;
    bf16* projw_bf = wb + 196608;
    bf16* w12f_bf  = wb + 262144;
    bf16* w2f_bf   = wb + 786432;
    float* biasTab = (float*)(ws + 2097152);           // 512 KiB
    bf16* Qb  = (bf16*)(ws + 2621440);                 // 64 MiB
    bf16* Kb  = (bf16*)(ws + 69730304);                // 64 MiB
    bf16* Vt  = (bf16*)(ws + 136839168);               // 64 MiB (V transposed)
    bf16* xn1 = (bf16*)(ws + 203948032);               // 64 MiB (reused as ao)
    bf16* ao  = (bf16*)(ws + 203948032);
    bf16* xn2 = (bf16*)(ws + 2621440);                 // over Qb (dead after attn)

    k_cvtw<<<512, 256, 0, stream>>>(qkvw, projw, fc12w, fc2w, wb);
    k_mkbias<<<512, 256, 0, stream>>>(rpb, biasTab);
    k_ln_win<<<32768, 256, 0, stream>>>(x, n1w, n1b, xn1);
    k_qkv<<<dim3(6, 1024), 256, 0, stream>>>(xn1, qkvw_bf, qkvb, Qb, Kb, Vt);
    k_attn<<<2048, 256, 0, stream>>>(Qb, Kb, Vt, biasTab, ao);
    k_proj<<<1024, 256, 0, stream>>>(ao, projw_bf, projb, x, n2w, n2b, out, xn2);
    k_mlp<<<1024, 512, 0, stream>>>(xn2, w12f_bf, fc12b, w2f_bf, fc2b, out);
}